// Round 13
// baseline (939.259 us; speedup 1.0000x reference)
//
#include <hip/hip_runtime.h>
#include <hip/hip_bf16.h>

#define NN 50000
#define NE 160000
#define NT 8192
#define DD 32
#define AA 6

typedef __attribute__((ext_vector_type(8))) short bf16x8s;
typedef __attribute__((ext_vector_type(4))) float f32x4;

// ---- static device scratch ----
__device__ float g_out[NN * DD];          // node features / GRU hidden (6.4 MB)
__device__ float g_msg[NE * DD];          // per-edge messages, dst-sorted (20.5 MB)
__device__ unsigned int g_h2b[NE * 16];   // relu(edge_attr@nn1_w+b), sorted order, bf16 pairs
__device__ int g_src[NE];                 // src node of sorted edge
__device__ int g_poe[NE];                 // original edge index of sorted position
__device__ unsigned int g_bcnt[NN];       // histogram bins
__device__ unsigned int g_row[NN + 1];    // CSR row_ptr (by dst)
__device__ unsigned int g_cur[NN];        // scatter cursors
__device__ unsigned int g_btot[256], g_boff[256];
__device__ bf16x8s g_w2frag[33 * 2 * 64]; // prepacked W2 B-frags (66 KB, L2-resident)
__device__ bf16x8s g_gru_frag[28 * 64];   // prepacked GRU B-frags hi/lo (28 KB)
__device__ float g_hl[DD], g_cl[DD];
__device__ float g_qs[6][DD];             // per-step q (q[0] from prep0)
__device__ float g_parts[6][DD + 1];      // per-step attention partials
__device__ unsigned int g_done[8];        // per-step completion counters
__device__ unsigned int g_gen;            // generation for step chaining

__device__ __forceinline__ float sigm(float x) { return 1.0f / (1.0f + __expf(-x)); }
__device__ __forceinline__ float tanhx(float x) { return 1.0f - 2.0f / (__expf(2.0f * x) + 1.0f); }
__device__ __forceinline__ unsigned short f2bf(float f) {
    unsigned int u = __float_as_uint(f);
    u = (u + 0x7fffu + ((u >> 16) & 1u)) >> 16;
    return (unsigned short)u;
}
__device__ __forceinline__ float bflo(unsigned int pk) { return __uint_as_float(pk << 16); }
__device__ __forceinline__ float bfhi(unsigned int pk) { return __uint_as_float(pk & 0xffff0000u); }
__device__ __forceinline__ void fma4(float4& a, float s, const float4 b) {
    a.x = fmaf(s, b.x, a.x); a.y = fmaf(s, b.y, a.y);
    a.z = fmaf(s, b.z, a.z); a.w = fmaf(s, b.w, a.w);
}
#define CVTPK(dst, lo, hi) asm("v_cvt_pk_bf16_f32 %0, %1, %2" : "=v"(dst) : "v"(lo), "v"(hi))
#define ALOAD(p)     __hip_atomic_load((p), __ATOMIC_RELAXED, __HIP_MEMORY_SCOPE_AGENT)
#define ASTORE(p, v) __hip_atomic_store((p), (v), __ATOMIC_RELAXED, __HIP_MEMORY_SCOPE_AGENT)

// split f32[8] into bf16 hi + bf16 residual-lo fragments (f32-equivalent via 3 MFMAs)
__device__ __forceinline__ void split8(const float* v, bf16x8s& hi, bf16x8s& lo) {
    union U { bf16x8s v; unsigned int u[4]; } H, L;
    CVTPK(H.u[0], v[0], v[1]); CVTPK(H.u[1], v[2], v[3]);
    CVTPK(H.u[2], v[4], v[5]); CVTPK(H.u[3], v[6], v[7]);
    float r[8];
#pragma unroll
    for (int q = 0; q < 4; ++q) {
        r[2 * q]     = v[2 * q]     - bflo(H.u[q]);
        r[2 * q + 1] = v[2 * q + 1] - bfhi(H.u[q]);
    }
    CVTPK(L.u[0], r[0], r[1]); CVTPK(L.u[1], r[2], r[3]);
    CVTPK(L.u[2], r[4], r[5]); CVTPK(L.u[3], r[6], r[7]);
    hi = H.v; lo = L.v;
}

// ---------- fused prep: init features + zero hist/sync state + frag prepack + LSTM step0 ----------
__global__ __launch_bounds__(256) void k_prep0(const float* __restrict__ x,
                                               const float* __restrict__ l0w,
                                               const float* __restrict__ l0b,
                                               const float* __restrict__ w2m,
                                               const float* __restrict__ b2m,
                                               const float* __restrict__ root,
                                               const float* __restrict__ wih,
                                               const float* __restrict__ whh,
                                               const float* __restrict__ lbih,
                                               const float* __restrict__ lbhh) {
    const int t = blockIdx.x * 256 + threadIdx.x;   // grid = NN*DD/256 = 6250 blocks
    {   // node init (all t)
        const int n = t >> 5, d = t & 31;
        float v = l0b[d];
        v = fmaf(x[n * 3 + 0], l0w[0 * DD + d], v);
        v = fmaf(x[n * 3 + 1], l0w[1 * DD + d], v);
        v = fmaf(x[n * 3 + 2], l0w[2 * DD + d], v);
        g_out[t] = fmaxf(v, 0.f);
    }
    if (t < NN) g_bcnt[t] = 0u;
    if (t < 33 * 2 * 64 * 8) {   // W2' frag prepack
        const int j = t & 7, l = (t >> 3) & 63, c = (t >> 9) & 1, s = t >> 10;
        const int kk = (l >> 4) * 8 + j;
        const int col = c * 16 + (l & 15);
        const float v = (s == 32) ? b2m[kk * DD + col] : w2m[(32 * s + kk) * DD + col];
        ((unsigned short*)g_w2frag)[t] = f2bf(v);
    }
    if (t < 28 * 64) {           // GRU frag prepack (hi/lo)
        const int lane = t & 63, f = t >> 6;
        const float* M; int ncols, c, part;
        if (f < 4)       { M = root; ncols = 32; c = f >> 1;        part = f & 1; }
        else if (f < 16) { M = wih;  ncols = 96; c = (f - 4) >> 1;  part = f & 1; }
        else             { M = whh;  ncols = 96; c = (f - 16) >> 1; part = f & 1; }
        unsigned short out8[8];
#pragma unroll
        for (int j = 0; j < 8; ++j) {
            const int k = (lane >> 4) * 8 + j;
            const float v = M[k * ncols + c * 16 + (lane & 15)];
            const unsigned short hi = f2bf(v);
            out8[j] = (part == 0) ? hi : f2bf(v - __uint_as_float((unsigned int)hi << 16));
        }
        g_gru_frag[f * 64 + lane] = *(bf16x8s*)out8;
    }
    if (t < DD) {                // Set2Set LSTM step 0 (biases only)
        const float ig = sigm(lbih[t] + lbhh[t]);
        const float g2 = tanhx(lbih[2 * DD + t] + lbhh[2 * DD + t]);
        const float og = sigm(lbih[3 * DD + t] + lbhh[3 * DD + t]);
        const float cc = ig * g2;
        g_cl[t] = cc; const float hn = og * tanhx(cc); g_hl[t] = hn;
        ASTORE(&g_qs[0][t], hn);
    }
    if (t < 6 * (DD + 1)) ASTORE(&((float*)g_parts)[t], 0.f);   // zero all step partials
    if (t >= 512 && t < 520) g_done[t - 512] = 0u;              // zero step counters
    if (t == 520) ASTORE(&g_gen, 0u);
}

// ---------- one-time sort of edges by dst (counting sort, CSR) ----------
__global__ __launch_bounds__(256) void k_hist(const int* __restrict__ ei) {
    const int e = blockIdx.x * 256 + threadIdx.x;   // exact E
    atomicAdd(&g_bcnt[ei[NE + e]], 1u);
}

__global__ __launch_bounds__(256) void k_scanA() {
    __shared__ unsigned int s[256];
    const int t = threadIdx.x;
    const int idx = blockIdx.x * 256 + t;
    const unsigned int c = (idx < NN) ? g_bcnt[idx] : 0u;
    s[t] = c;
    __syncthreads();
#pragma unroll
    for (int off = 1; off < 256; off <<= 1) {
        const unsigned int o = (t >= off) ? s[t - off] : 0u;
        __syncthreads();
        s[t] += o;
        __syncthreads();
    }
    if (idx < NN) g_row[idx] = s[t] - c;   // block-local exclusive
    if (t == 255) g_btot[blockIdx.x] = s[255];
}

__global__ void k_scanB() {
    __shared__ unsigned int s[256];
    const int t = threadIdx.x;   // 256
    const unsigned int c = (t < 196) ? g_btot[t] : 0u;
    s[t] = c;
    __syncthreads();
#pragma unroll
    for (int off = 1; off < 256; off <<= 1) {
        const unsigned int o = (t >= off) ? s[t - off] : 0u;
        __syncthreads();
        s[t] += o;
        __syncthreads();
    }
    if (t < 196) g_boff[t] = s[t] - c;
}

__global__ __launch_bounds__(256) void k_scanC() {
    const int idx = blockIdx.x * 256 + threadIdx.x;
    if (idx < NN) {
        const unsigned int v = g_row[idx] + g_boff[blockIdx.x];
        g_row[idx] = v;
        g_cur[idx] = v;
    }
    if (idx == 0) g_row[NN] = NE;
}

__global__ __launch_bounds__(256) void k_scatter(const int* __restrict__ ei) {
    const int e = blockIdx.x * 256 + threadIdx.x;   // exact E
    const int d = ei[NE + e];
    const unsigned int pos = atomicAdd(&g_cur[d], 1u);
    g_src[pos] = ei[e];
    g_poe[pos] = e;
}

// h2 = relu(edge_attr @ nn1_w + nn1_b) in SORTED edge order, packed bf16 pairs
__global__ __launch_bounds__(256) void k_h2(const float* __restrict__ ea,
                                            const float* __restrict__ w,
                                            const float* __restrict__ b) {
    const int t = blockIdx.x * 256 + threadIdx.x;   // exact E*16
    const int p = t >> 4, kp = t & 15;
    const int oe = g_poe[p];
    const int k0 = kp * 2;
    float a0 = b[k0], a1 = b[k0 + 1];
#pragma unroll
    for (int i = 0; i < 7; ++i) {
        const float eav = ea[oe * 7 + i];
        a0 = fmaf(eav, w[i * DD + k0], a0);
        a1 = fmaf(eav, w[i * DD + k0 + 1], a1);
    }
    unsigned int pk;
    CVTPK(pk, fmaxf(a0, 0.f), fmaxf(a1, 0.f));
    g_h2b[t] = pk;
}

// Fused NNConv edge pass via MFMA: msg = z @ W2', z = h2 (x) u in registers.
// Edges dst-sorted; msg written contiguously — ZERO atomics. (round-8 verified)
__global__ __launch_bounds__(256) void k_edge_mfma() {
    const int wid = threadIdx.x >> 6, lane = threadIdx.x & 63;
    const int w = blockIdx.x * 4 + wid;              // 0..4999
    const int col = lane & 15, quad = lane >> 4;
    const bf16x8s* __restrict__ B = g_w2frag;

    const bf16x8s bbias0 = B[32 * 128 + lane];
    const bf16x8s bbias1 = B[32 * 128 + 64 + lane];

    float4 u0[2], u1[2];
    unsigned int h2p[2][16];
#pragma unroll
    for (int g = 0; g < 2; ++g) {
        const int e = w * 32 + g * 16 + col;
        const int src = g_src[e];
        u0[g] = *(const float4*)&g_out[src * DD + quad * 8];
        u1[g] = *(const float4*)&g_out[src * DD + quad * 8 + 4];
        *(uint4*)&h2p[g][0]  = *(const uint4*)&g_h2b[e * 16];
        *(uint4*)&h2p[g][4]  = *(const uint4*)&g_h2b[e * 16 + 4];
        *(uint4*)&h2p[g][8]  = *(const uint4*)&g_h2b[e * 16 + 8];
        *(uint4*)&h2p[g][12] = *(const uint4*)&g_h2b[e * 16 + 12];
    }

    union ABu { bf16x8s v; unsigned int u[4]; };
    f32x4 acc[2][2];
#pragma unroll
    for (int g = 0; g < 2; ++g) {
        acc[g][0] = (f32x4){0.f, 0.f, 0.f, 0.f};
        acc[g][1] = (f32x4){0.f, 0.f, 0.f, 0.f};
    }

#define EDGE_STEP(S, B0V, B1V)                                                                   \
    do {                                                                                          \
        _Pragma("unroll")                                                                         \
        for (int g = 0; g < 2; ++g) {                                                             \
            const unsigned int hw = h2p[g][(S) >> 1];                                             \
            const float hs = ((S)&1) ? bfhi(hw) : bflo(hw);                                       \
            ABu A;                                                                                \
            CVTPK(A.u[0], hs * u0[g].x, hs * u0[g].y);                                            \
            CVTPK(A.u[1], hs * u0[g].z, hs * u0[g].w);                                            \
            CVTPK(A.u[2], hs * u1[g].x, hs * u1[g].y);                                            \
            CVTPK(A.u[3], hs * u1[g].z, hs * u1[g].w);                                            \
            acc[g][0] = __builtin_amdgcn_mfma_f32_16x16x32_bf16(A.v, B0V, acc[g][0], 0, 0, 0);    \
            acc[g][1] = __builtin_amdgcn_mfma_f32_16x16x32_bf16(A.v, B1V, acc[g][1], 0, 0, 0);    \
        }                                                                                         \
    } while (0)

    bf16x8s ca0 = B[0 * 128 + lane], cb0 = B[0 * 128 + 64 + lane];
    bf16x8s ca1 = B[1 * 128 + lane], cb1 = B[1 * 128 + 64 + lane];
    bf16x8s ca2 = B[2 * 128 + lane], cb2 = B[2 * 128 + 64 + lane];
    bf16x8s ca3 = B[3 * 128 + lane], cb3 = B[3 * 128 + 64 + lane];
    bf16x8s na0, nb0, na1, nb1, na2, nb2, na3, nb3;

#pragma unroll
    for (int blk = 0; blk < 8; ++blk) {
        if (blk < 7) {
            const int r = blk * 4 + 4;
            na0 = B[(r + 0) * 128 + lane]; nb0 = B[(r + 0) * 128 + 64 + lane];
            na1 = B[(r + 1) * 128 + lane]; nb1 = B[(r + 1) * 128 + 64 + lane];
            na2 = B[(r + 2) * 128 + lane]; nb2 = B[(r + 2) * 128 + 64 + lane];
            na3 = B[(r + 3) * 128 + lane]; nb3 = B[(r + 3) * 128 + 64 + lane];
        }
        EDGE_STEP(blk * 4 + 0, ca0, cb0);
        EDGE_STEP(blk * 4 + 1, ca1, cb1);
        EDGE_STEP(blk * 4 + 2, ca2, cb2);
        EDGE_STEP(blk * 4 + 3, ca3, cb3);
        if (blk < 7) {
            ca0 = na0; cb0 = nb0; ca1 = na1; cb1 = nb1;
            ca2 = na2; cb2 = nb2; ca3 = na3; cb3 = nb3;
        }
    }
#undef EDGE_STEP

    {   // bias step
#pragma unroll
        for (int g = 0; g < 2; ++g) {
            ABu Au;
            CVTPK(Au.u[0], u0[g].x, u0[g].y); CVTPK(Au.u[1], u0[g].z, u0[g].w);
            CVTPK(Au.u[2], u1[g].x, u1[g].y); CVTPK(Au.u[3], u1[g].z, u1[g].w);
            acc[g][0] = __builtin_amdgcn_mfma_f32_16x16x32_bf16(Au.v, bbias0, acc[g][0], 0, 0, 0);
            acc[g][1] = __builtin_amdgcn_mfma_f32_16x16x32_bf16(Au.v, bbias1, acc[g][1], 0, 0, 0);
        }
    }
#pragma unroll
    for (int g = 0; g < 2; ++g)
#pragma unroll
        for (int r = 0; r < 4; ++r) {
            const int p = w * 32 + g * 16 + quad * 4 + r;
            g_msg[p * DD + col] = acc[g][0][r];
            g_msg[p * DD + 16 + col] = acc[g][1][r];
        }
}

// GRU node update via MFMA (split-bf16). msg segment-sum via coalesced LDS staging.
__global__ __launch_bounds__(256) void k_node_mfma(const float* __restrict__ cb,
                                                   const float* __restrict__ bih,
                                                   const float* __restrict__ bhh) {
    __shared__ float sm[4][16 * 36];      // m-transpose tile (pad 36)
    __shared__ float smsg[4][16 * 32];    // staged msg chunk per wave
    const int wid = threadIdx.x >> 6, lane = threadIdx.x & 63;
    const int nt = blockIdx.x * 4 + wid;
    if (nt >= NN / 16) return;            // 3125 tiles exactly
    const int nb = nt * 16;
    const int col = lane & 15, quad = lane >> 4;
    const bf16x8s* FB = g_gru_frag;
    float* smt = sm[wid];
    float* smm = smsg[wid];

    float hv8[8];
    *(float4*)&hv8[0] = *(const float4*)&g_out[(nb + col) * DD + quad * 8];
    *(float4*)&hv8[4] = *(const float4*)&g_out[(nb + col) * DD + quad * 8 + 4];
    bf16x8s hAh, hAl; split8(hv8, hAh, hAl);

    unsigned int nr0[4], nr1[4];
#pragma unroll
    for (int r = 0; r < 4; ++r) {
        const int node = nb + quad * 4 + r;
        nr0[r] = g_row[node];
        nr1[r] = g_row[node + 1];
    }
    const unsigned int e0t = g_row[nb], e1t = g_row[nb + 16];

    float agg0[4] = {0.f, 0.f, 0.f, 0.f};
    float agg1[4] = {0.f, 0.f, 0.f, 0.f};
    for (unsigned int ec = e0t; ec < e1t; ec += 16) {
        const int idx = min((int)ec * 32 + lane * 8, NE * 32 - 8);
        const float4 v0 = *(const float4*)&g_msg[idx];
        const float4 v1 = *(const float4*)&g_msg[idx + 4];
        *(float4*)&smm[lane * 8] = v0;
        *(float4*)&smm[lane * 8 + 4] = v1;
#pragma unroll
        for (int r = 0; r < 4; ++r) {
            const int lo = (int)max(nr0[r], ec) - (int)ec;
            const int hi = (int)min(nr1[r], ec + 16u) - (int)ec;
            for (int s = lo; s < hi; ++s) {
                agg0[r] += smm[s * 32 + col];
                agg1[r] += smm[s * 32 + 16 + col];
            }
        }
    }

    float invr[4];
#pragma unroll
    for (int r = 0; r < 4; ++r)
        invr[r] = 1.0f / fmaxf((float)(nr1[r] - nr0[r]), 1.0f);

    // m = relu(h@root + agg*inv + cb), D-layout (row = quad*4+r, col)
#pragma unroll
    for (int c = 0; c < 2; ++c) {
        const float cbv = cb[c * 16 + col];
        f32x4 aM;
#pragma unroll
        for (int r = 0; r < 4; ++r)
            aM[r] = fmaf((c == 0) ? agg0[r] : agg1[r], invr[r], cbv);
        const bf16x8s Bh = FB[(c * 2 + 0) * 64 + lane];
        const bf16x8s Bl = FB[(c * 2 + 1) * 64 + lane];
        aM = __builtin_amdgcn_mfma_f32_16x16x32_bf16(hAh, Bh, aM, 0, 0, 0);
        aM = __builtin_amdgcn_mfma_f32_16x16x32_bf16(hAl, Bh, aM, 0, 0, 0);
        aM = __builtin_amdgcn_mfma_f32_16x16x32_bf16(hAh, Bl, aM, 0, 0, 0);
#pragma unroll
        for (int r = 0; r < 4; ++r)
            smt[(quad * 4 + r) * 36 + c * 16 + col] = fmaxf(aM[r], 0.f);
    }

    float mv8[8];
    *(float4*)&mv8[0] = *(const float4*)&smt[col * 36 + quad * 8];
    *(float4*)&mv8[4] = *(const float4*)&smt[col * 36 + quad * 8 + 4];
    bf16x8s mAh, mAl; split8(mv8, mAh, mAl);

    f32x4 R[2], Z[2], XN[2], HN[2];
#pragma unroll
    for (int c = 0; c < 6; ++c) {
        const float bx = bih[c * 16 + col], bh = bhh[c * 16 + col];
        f32x4 aX = {bx, bx, bx, bx}, aH = {bh, bh, bh, bh};
        const bf16x8s WIhf = FB[(4 + c * 2) * 64 + lane];
        const bf16x8s WIlf = FB[(5 + c * 2) * 64 + lane];
        const bf16x8s WHhf = FB[(16 + c * 2) * 64 + lane];
        const bf16x8s WHlf = FB[(17 + c * 2) * 64 + lane];
        aX = __builtin_amdgcn_mfma_f32_16x16x32_bf16(mAh, WIhf, aX, 0, 0, 0);
        aX = __builtin_amdgcn_mfma_f32_16x16x32_bf16(mAl, WIhf, aX, 0, 0, 0);
        aX = __builtin_amdgcn_mfma_f32_16x16x32_bf16(mAh, WIlf, aX, 0, 0, 0);
        aH = __builtin_amdgcn_mfma_f32_16x16x32_bf16(hAh, WHhf, aH, 0, 0, 0);
        aH = __builtin_amdgcn_mfma_f32_16x16x32_bf16(hAl, WHhf, aH, 0, 0, 0);
        aH = __builtin_amdgcn_mfma_f32_16x16x32_bf16(hAh, WHlf, aH, 0, 0, 0);
        if (c < 2) {
#pragma unroll
            for (int r = 0; r < 4; ++r) R[c][r] = sigm(aX[r] + aH[r]);
        } else if (c < 4) {
#pragma unroll
            for (int r = 0; r < 4; ++r) Z[c - 2][r] = sigm(aX[r] + aH[r]);
        } else {
            XN[c - 4] = aX; HN[c - 4] = aH;
        }
    }
#pragma unroll
    for (int c = 0; c < 2; ++c)
#pragma unroll
        for (int r = 0; r < 4; ++r) {
            const int addr = (nb + quad * 4 + r) * DD + c * 16 + col;
            const float nv = tanhx(XN[c][r] + R[c][r] * HN[c][r]);
            const float hv = g_out[addr];
            g_out[addr] = (1.f - Z[c][r]) * nv + Z[c][r] * hv;
        }
}

// ---------- Set2Set: 6 attention passes + 5 LSTM steps in ONE ordinary dispatch ----------
// Chaining via generation counter + per-step completion counters (the k_att_f protocol,
// proven over 10 rounds, extended). NO cooperative launch. All blocks co-resident (196).
__global__ __launch_bounds__(256) void k_s2s_spin(const float* __restrict__ wih,
                                                  const float* __restrict__ whh,
                                                  const float* __restrict__ bih,
                                                  const float* __restrict__ bhh) {
    __shared__ float sq[DD];
    __shared__ float red[4][DD + 1];
    __shared__ int slast;
    __shared__ float qs[64], shl[DD], gg[128];
    const int lwid = threadIdx.x >> 6, lane = threadIdx.x & 63;

    for (int s = 0; s < 6; ++s) {
        // wait until step s's q is published
        if (threadIdx.x == 0) {
            while ((int)__hip_atomic_load(&g_gen, __ATOMIC_ACQUIRE, __HIP_MEMORY_SCOPE_AGENT) < s)
                __builtin_amdgcn_s_sleep(8);
        }
        __syncthreads();
        if (threadIdx.x < DD) sq[threadIdx.x] = ALOAD(&g_qs[s][threadIdx.x]);
        __syncthreads();

        float pe = 0.f;
        float pv[DD];
#pragma unroll
        for (int i = 0; i < DD; ++i) pv[i] = 0.f;
        for (int n = blockIdx.x * 256 + threadIdx.x; n < NN; n += gridDim.x * 256) {
            float row[DD];
#pragma unroll
            for (int q = 0; q < 8; ++q) *(float4*)&row[4 * q] = *(const float4*)&g_out[n * DD + 4 * q];
            float dot = 0.f;
#pragma unroll
            for (int i = 0; i < DD; ++i) dot = fmaf(row[i], sq[i], dot);
            const float e = __expf(dot);
            pe += e;
#pragma unroll
            for (int i = 0; i < DD; ++i) pv[i] = fmaf(e, row[i], pv[i]);
        }
#pragma unroll
        for (int off = 32; off > 0; off >>= 1) {
            pe += __shfl_down(pe, off, 64);
#pragma unroll
            for (int i = 0; i < DD; ++i) pv[i] += __shfl_down(pv[i], off, 64);
        }
        if (lane == 0) {
            red[lwid][0] = pe;
#pragma unroll
            for (int i = 0; i < DD; ++i) red[lwid][1 + i] = pv[i];
        }
        __syncthreads();
        if (threadIdx.x < DD + 1) {
            const float sv = red[0][threadIdx.x] + red[1][threadIdx.x] + red[2][threadIdx.x] + red[3][threadIdx.x];
            atomicAdd(&g_parts[s][threadIdx.x], sv);
        }
        __threadfence();
        __syncthreads();
        if (threadIdx.x == 0) {
            const unsigned int o = atomicAdd(&g_done[s], 1u);
            slast = (o == (unsigned int)(gridDim.x - 1)) ? 1 : 0;
        }
        __syncthreads();

        if (slast && s < 5) {   // last-finishing block runs the LSTM for step s+1
            __threadfence();
            const int t = threadIdx.x;
            if (t < DD) { qs[t] = sq[t]; shl[t] = ALOAD(&g_hl[t]); }
            else if (t < 64) qs[t] = ALOAD(&g_parts[s][1 + t - DD]) / ALOAD(&g_parts[s][0]);
            __syncthreads();
            if (t < 128) {
                float acc = bih[t] + bhh[t];
                for (int i = 0; i < 64; ++i) acc = fmaf(qs[i], wih[i * 128 + t], acc);
                for (int i = 0; i < DD; ++i) acc = fmaf(shl[i], whh[i * 128 + t], acc);
                gg[t] = acc;
            }
            __syncthreads();
            if (t < DD) {
                const float ig = sigm(gg[t]), fg = sigm(gg[DD + t]);
                const float g2 = tanhx(gg[2 * DD + t]), og = sigm(gg[3 * DD + t]);
                const float cc = fmaf(fg, ALOAD(&g_cl[t]), ig * g2);
                ASTORE(&g_cl[t], cc);
                const float hn = og * tanhx(cc);
                ASTORE(&g_hl[t], hn);
                ASTORE(&g_qs[s + 1][t], hn);
            }
            __threadfence();
            __syncthreads();
            if (t == 0)
                __hip_atomic_store(&g_gen, (unsigned int)(s + 1), __ATOMIC_RELEASE,
                                   __HIP_MEMORY_SCOPE_AGENT);
        }
    }
}

// readout: 256 blocks x 128 threads, p-loop split 4-way across lane-slices
__global__ __launch_bounds__(128) void k_readout(const int* __restrict__ nr,
                                                 const float* __restrict__ w1,
                                                 const float* __restrict__ b1,
                                                 const float* __restrict__ w2,
                                                 const float* __restrict__ b2,
                                                 float* __restrict__ yout) {
    __shared__ float sw1[192 * DD];
    __shared__ float sS1[DD];
    __shared__ float sw2[DD * AA];
    __shared__ float sb1[DD];
    __shared__ float sb2[AA];
    __shared__ float sred[32 * DD];
    for (int i = threadIdx.x; i < 192 * DD; i += 128) sw1[i] = w1[i];
    for (int i = threadIdx.x; i < DD * AA; i += 128) sw2[i] = w2[i];
    if (threadIdx.x < DD) sb1[threadIdx.x] = b1[threadIdx.x];
    if (threadIdx.x >= DD && threadIdx.x < DD + AA) sb2[threadIdx.x - DD] = b2[threadIdx.x - DD];
    __syncthreads();
    if (threadIdx.x < DD) {
        float s = 0.f;
        for (int c = 0; c < 64; ++c) s += sw1[(128 + c) * DD + threadIdx.x];
        sS1[threadIdx.x] = s;
    }
    __syncthreads();
    const int g = blockIdx.x;            // t-group 0..255
    const int t0 = g * 32;
    const int f = threadIdx.x & 31;      // t-offset == feature index
    const int slice = threadIdx.x >> 5;  // 0..3 p-slices
    const int rowbase = g >> 2, col = g & 3;
    float4 acc[8];
#pragma unroll
    for (int q = 0; q < 8; ++q) acc[q] = make_float4(0.f, 0.f, 0.f, 0.f);
    for (int pp = 0; pp < 32; ++pp) {
        const int p = slice * 32 + pp;
        const int node = nr[(p * 64 + rowbase) * 4 + col];
        const float v = g_out[node * DD + f];
#pragma unroll
        for (int q = 0; q < 8; ++q) fma4(acc[q], v, *(const float4*)&sw1[p * DD + 4 * q]);
    }
#pragma unroll
    for (int q = 0; q < 8; ++q) {
        acc[q].x += __shfl_xor(acc[q].x, 32, 64);
        acc[q].y += __shfl_xor(acc[q].y, 32, 64);
        acc[q].z += __shfl_xor(acc[q].z, 32, 64);
        acc[q].w += __shfl_xor(acc[q].w, 32, 64);
    }
    if (threadIdx.x >= 64 && threadIdx.x < 96) {
#pragma unroll
        for (int q = 0; q < 8; ++q) *(float4*)&sred[f * DD + 4 * q] = acc[q];
    }
    __syncthreads();
    if (threadIdx.x < 32) {
        const int pidx = g >> 2;
        const float poolv = (pidx < DD) ? g_qs[5][pidx]
                                        : (g_parts[5][1 + (pidx - DD)] / g_parts[5][0]);
        float y[AA];
#pragma unroll
        for (int a = 0; a < AA; ++a) y[a] = sb2[a];
#pragma unroll
        for (int q = 0; q < 8; ++q) {
            const float4 o = *(const float4*)&sred[f * DD + 4 * q];
            const float vals[4] = {acc[q].x + o.x, acc[q].y + o.y, acc[q].z + o.z, acc[q].w + o.w};
#pragma unroll
            for (int cc = 0; cc < 4; ++cc) {
                const int d = 4 * q + cc;
                const float ad = fmaxf(fmaf(poolv, sS1[d], sb1[d]) + vals[cc], 0.f);
#pragma unroll
                for (int a = 0; a < AA; ++a) y[a] = fmaf(ad, sw2[d * AA + a], y[a]);
            }
        }
#pragma unroll
        for (int a = 0; a < AA; ++a) yout[(t0 + f) * AA + a] = y[a];
    }
}

extern "C" void kernel_launch(void* const* d_in, const int* in_sizes, int n_in,
                              void* d_out, int out_size, void* d_ws, size_t ws_size,
                              hipStream_t stream) {
    (void)in_sizes; (void)n_in; (void)out_size; (void)d_ws; (void)ws_size;
    const float* x        = (const float*)d_in[0];
    const int*   ei       = (const int*)d_in[1];
    const float* ea       = (const float*)d_in[2];
    const int*   nonring  = (const int*)d_in[3];
    const float* lin0_w   = (const float*)d_in[4];
    const float* lin0_b   = (const float*)d_in[5];
    const float* nn1_w    = (const float*)d_in[6];
    const float* nn1_b    = (const float*)d_in[7];
    const float* nn2_w    = (const float*)d_in[8];
    const float* nn2_b    = (const float*)d_in[9];
    const float* conv_root= (const float*)d_in[10];
    const float* conv_b   = (const float*)d_in[11];
    const float* gru_w_ih = (const float*)d_in[12];
    const float* gru_w_hh = (const float*)d_in[13];
    const float* gru_b_ih = (const float*)d_in[14];
    const float* gru_b_hh = (const float*)d_in[15];
    const float* lstm_w_ih= (const float*)d_in[16];
    const float* lstm_w_hh= (const float*)d_in[17];
    const float* lstm_b_ih= (const float*)d_in[18];
    const float* lstm_b_hh= (const float*)d_in[19];
    const float* lin1_w   = (const float*)d_in[20];
    const float* lin1_b   = (const float*)d_in[21];
    const float* lin2_w   = (const float*)d_in[22];
    const float* lin2_b   = (const float*)d_in[23];
    float* out = (float*)d_out;

    k_prep0<<<(NN * DD) / 256, 256, 0, stream>>>(x, lin0_w, lin0_b, nn2_w, nn2_b,
                                                 conv_root, gru_w_ih, gru_w_hh,
                                                 lstm_b_ih, lstm_b_hh);
    k_hist<<<NE / 256, 256, 0, stream>>>(ei);
    k_scanA<<<196, 256, 0, stream>>>();
    k_scanB<<<1, 256, 0, stream>>>();
    k_scanC<<<196, 256, 0, stream>>>();
    k_scatter<<<NE / 256, 256, 0, stream>>>(ei);
    k_h2<<<(NE * 16) / 256, 256, 0, stream>>>(ea, nn1_w, nn1_b);

    for (int it = 0; it < 6; ++it) {
        k_edge_mfma<<<1250, 256, 0, stream>>>();
        k_node_mfma<<<(NN / 16 + 3) / 4, 256, 0, stream>>>(conv_b, gru_b_ih, gru_b_hh);
    }

    k_s2s_spin<<<196, 256, 0, stream>>>(lstm_w_ih, lstm_w_hh, lstm_b_ih, lstm_b_hh);

    k_readout<<<256, 128, 0, stream>>>(nonring, lin1_w, lin1_b, lin2_w, lin2_b, out);
}

// Round 15
// 399.609 us; speedup vs baseline: 2.3504x; 2.3504x over previous
//
#include <hip/hip_runtime.h>
#include <hip/hip_bf16.h>

#define NN 50000
#define NE 160000
#define NT 8192
#define DD 32
#define AA 6

typedef __attribute__((ext_vector_type(8))) short bf16x8s;
typedef __attribute__((ext_vector_type(4))) float f32x4;

// ---- static device scratch ----
__device__ float g_out[NN * DD];          // node features / GRU hidden (6.4 MB)
__device__ float g_msg[NE * DD];          // per-edge messages, dst-sorted (20.5 MB)
__device__ unsigned int g_h2b[NE * 16];   // relu(edge_attr@nn1_w+b), sorted order, bf16 pairs
__device__ int g_src[NE];                 // src node of sorted edge
__device__ unsigned int g_bcnt[NN];       // histogram bins
__device__ unsigned int g_row[NN + 1];    // CSR row_ptr (by dst)
__device__ unsigned int g_cur[NN];        // scatter cursors
__device__ unsigned int g_btot[256], g_boff[256];
__device__ bf16x8s g_w2frag[33 * 2 * 64]; // prepacked W2 B-frags (66 KB, L2-resident)
__device__ bf16x8s g_gru_frag[28 * 64];   // prepacked GRU B-frags hi/lo (28 KB)
__device__ float g_hl[DD], g_cl[DD], g_q[DD], g_part[DD + 1];
__device__ unsigned int g_cnt;            // zero at module load; reset after each use

__device__ __forceinline__ float sigm(float x) { return 1.0f / (1.0f + __expf(-x)); }
__device__ __forceinline__ float tanhx(float x) { return 1.0f - 2.0f / (__expf(2.0f * x) + 1.0f); }
__device__ __forceinline__ unsigned short f2bf(float f) {
    unsigned int u = __float_as_uint(f);
    u = (u + 0x7fffu + ((u >> 16) & 1u)) >> 16;
    return (unsigned short)u;
}
__device__ __forceinline__ float bflo(unsigned int pk) { return __uint_as_float(pk << 16); }
__device__ __forceinline__ float bfhi(unsigned int pk) { return __uint_as_float(pk & 0xffff0000u); }
__device__ __forceinline__ void fma4(float4& a, float s, const float4 b) {
    a.x = fmaf(s, b.x, a.x); a.y = fmaf(s, b.y, a.y);
    a.z = fmaf(s, b.z, a.z); a.w = fmaf(s, b.w, a.w);
}
#define CVTPK(dst, lo, hi) asm("v_cvt_pk_bf16_f32 %0, %1, %2" : "=v"(dst) : "v"(lo), "v"(hi))
#define ALOAD(p)     __hip_atomic_load((p), __ATOMIC_RELAXED, __HIP_MEMORY_SCOPE_AGENT)
#define ASTORE(p, v) __hip_atomic_store((p), (v), __ATOMIC_RELAXED, __HIP_MEMORY_SCOPE_AGENT)

// split f32[8] into bf16 hi + bf16 residual-lo fragments (f32-equivalent via 3 MFMAs)
__device__ __forceinline__ void split8(const float* v, bf16x8s& hi, bf16x8s& lo) {
    union U { bf16x8s v; unsigned int u[4]; } H, L;
    CVTPK(H.u[0], v[0], v[1]); CVTPK(H.u[1], v[2], v[3]);
    CVTPK(H.u[2], v[4], v[5]); CVTPK(H.u[3], v[6], v[7]);
    float r[8];
#pragma unroll
    for (int q = 0; q < 4; ++q) {
        r[2 * q]     = v[2 * q]     - bflo(H.u[q]);
        r[2 * q + 1] = v[2 * q + 1] - bfhi(H.u[q]);
    }
    CVTPK(L.u[0], r[0], r[1]); CVTPK(L.u[1], r[2], r[3]);
    CVTPK(L.u[2], r[4], r[5]); CVTPK(L.u[3], r[6], r[7]);
    hi = H.v; lo = L.v;
}

// ---------- fused prep: init features + zero hist + W2/GRU frag prepack + LSTM step0 ----------
__global__ __launch_bounds__(256) void k_prep0(const float* __restrict__ x,
                                               const float* __restrict__ l0w,
                                               const float* __restrict__ l0b,
                                               const float* __restrict__ w2m,
                                               const float* __restrict__ b2m,
                                               const float* __restrict__ root,
                                               const float* __restrict__ wih,
                                               const float* __restrict__ whh,
                                               const float* __restrict__ lbih,
                                               const float* __restrict__ lbhh) {
    const int t = blockIdx.x * 256 + threadIdx.x;   // grid = NN*DD/256 = 6250 blocks
    {   // node init (all t)
        const int n = t >> 5, d = t & 31;
        float v = l0b[d];
        v = fmaf(x[n * 3 + 0], l0w[0 * DD + d], v);
        v = fmaf(x[n * 3 + 1], l0w[1 * DD + d], v);
        v = fmaf(x[n * 3 + 2], l0w[2 * DD + d], v);
        g_out[t] = fmaxf(v, 0.f);
    }
    if (t < NN) g_bcnt[t] = 0u;
    if (t < 33 * 2 * 64 * 8) {   // W2' frag prepack
        const int j = t & 7, l = (t >> 3) & 63, c = (t >> 9) & 1, s = t >> 10;
        const int kk = (l >> 4) * 8 + j;
        const int col = c * 16 + (l & 15);
        const float v = (s == 32) ? b2m[kk * DD + col] : w2m[(32 * s + kk) * DD + col];
        ((unsigned short*)g_w2frag)[t] = f2bf(v);
    }
    if (t < 28 * 64) {           // GRU frag prepack (hi/lo)
        const int lane = t & 63, f = t >> 6;
        const float* M; int ncols, c, part;
        if (f < 4)       { M = root; ncols = 32; c = f >> 1;        part = f & 1; }
        else if (f < 16) { M = wih;  ncols = 96; c = (f - 4) >> 1;  part = f & 1; }
        else             { M = whh;  ncols = 96; c = (f - 16) >> 1; part = f & 1; }
        unsigned short out8[8];
#pragma unroll
        for (int j = 0; j < 8; ++j) {
            const int k = (lane >> 4) * 8 + j;
            const float v = M[k * ncols + c * 16 + (lane & 15)];
            const unsigned short hi = f2bf(v);
            out8[j] = (part == 0) ? hi : f2bf(v - __uint_as_float((unsigned int)hi << 16));
        }
        g_gru_frag[f * 64 + lane] = *(bf16x8s*)out8;
    }
    if (t < DD) {                // Set2Set LSTM step 0 (biases only)
        const float ig = sigm(lbih[t] + lbhh[t]);
        const float g2 = tanhx(lbih[2 * DD + t] + lbhh[2 * DD + t]);
        const float og = sigm(lbih[3 * DD + t] + lbhh[3 * DD + t]);
        const float cc = ig * g2;
        g_cl[t] = cc; const float hn = og * tanhx(cc); g_hl[t] = hn;
        ASTORE(&g_q[t], hn);
    }
    if (t >= DD && t <= 2 * DD) ASTORE(&g_part[t - DD], 0.f);   // exactly DD+1 entries
    if (t == 520) ASTORE(&g_cnt, 0u);
}

// ---------- one-time sort of edges by dst (counting sort, CSR) ----------
__global__ __launch_bounds__(256) void k_hist(const int* __restrict__ ei) {
    const int e = blockIdx.x * 256 + threadIdx.x;   // exact E
    atomicAdd(&g_bcnt[ei[NE + e]], 1u);
}

__global__ __launch_bounds__(256) void k_scanA() {
    __shared__ unsigned int s[256];
    const int t = threadIdx.x;
    const int idx = blockIdx.x * 256 + t;
    const unsigned int c = (idx < NN) ? g_bcnt[idx] : 0u;
    s[t] = c;
    __syncthreads();
#pragma unroll
    for (int off = 1; off < 256; off <<= 1) {
        const unsigned int o = (t >= off) ? s[t - off] : 0u;
        __syncthreads();
        s[t] += o;
        __syncthreads();
    }
    if (idx < NN) g_row[idx] = s[t] - c;   // block-local exclusive
    if (t == 255) g_btot[blockIdx.x] = s[255];
}

__global__ void k_scanB() {
    __shared__ unsigned int s[256];
    const int t = threadIdx.x;   // 256
    const unsigned int c = (t < 196) ? g_btot[t] : 0u;
    s[t] = c;
    __syncthreads();
#pragma unroll
    for (int off = 1; off < 256; off <<= 1) {
        const unsigned int o = (t >= off) ? s[t - off] : 0u;
        __syncthreads();
        s[t] += o;
        __syncthreads();
    }
    if (t < 196) g_boff[t] = s[t] - c;
}

__global__ __launch_bounds__(256) void k_scanC() {
    const int idx = blockIdx.x * 256 + threadIdx.x;
    if (idx < NN) {
        const unsigned int v = g_row[idx] + g_boff[blockIdx.x];
        g_row[idx] = v;
        g_cur[idx] = v;
    }
    if (idx == 0) g_row[NN] = NE;
}

// scatter + fused h2: write src and relu(edge_attr@nn1_w+nn1_b) at the sorted position
__global__ __launch_bounds__(256) void k_scatter(const int* __restrict__ ei,
                                                 const float* __restrict__ ea,
                                                 const float* __restrict__ w,
                                                 const float* __restrict__ b) {
    const int e = blockIdx.x * 256 + threadIdx.x;   // exact E
    const int d = ei[NE + e];
    const unsigned int pos = atomicAdd(&g_cur[d], 1u);
    g_src[pos] = ei[e];
    float eav[7];
#pragma unroll
    for (int i = 0; i < 7; ++i) eav[i] = ea[e * 7 + i];
#pragma unroll
    for (int kp = 0; kp < 16; ++kp) {
        const int k0 = kp * 2;
        float a0 = b[k0], a1 = b[k0 + 1];
#pragma unroll
        for (int i = 0; i < 7; ++i) {
            a0 = fmaf(eav[i], w[i * DD + k0], a0);
            a1 = fmaf(eav[i], w[i * DD + k0 + 1], a1);
        }
        unsigned int pk;
        CVTPK(pk, fmaxf(a0, 0.f), fmaxf(a1, 0.f));
        g_h2b[(size_t)pos * 16 + kp] = pk;
    }
}

// Fused NNConv edge pass via MFMA: msg = z @ W2', z = h2 (x) u in registers.
// G=2 groups (32 edges)/wave, named-register double-buffered B pipeline. (round-7/8/11 verified)
__global__ __launch_bounds__(256) void k_edge_mfma() {
    const int wid = threadIdx.x >> 6, lane = threadIdx.x & 63;
    const int w = blockIdx.x * 4 + wid;              // 0..4999 (1250 blocks x 4 waves)
    const int col = lane & 15, quad = lane >> 4;
    const bf16x8s* __restrict__ B = g_w2frag;

    // bias row (consumed last) issued FIRST: ~30 steps of latency slack
    const bf16x8s bbias0 = B[32 * 128 + lane];
    const bf16x8s bbias1 = B[32 * 128 + 64 + lane];

    float4 u0[2], u1[2];
    unsigned int h2p[2][16];
#pragma unroll
    for (int g = 0; g < 2; ++g) {
        const int e = w * 32 + g * 16 + col;
        const int src = g_src[e];
        u0[g] = *(const float4*)&g_out[src * DD + quad * 8];
        u1[g] = *(const float4*)&g_out[src * DD + quad * 8 + 4];
        *(uint4*)&h2p[g][0]  = *(const uint4*)&g_h2b[(size_t)e * 16];
        *(uint4*)&h2p[g][4]  = *(const uint4*)&g_h2b[(size_t)e * 16 + 4];
        *(uint4*)&h2p[g][8]  = *(const uint4*)&g_h2b[(size_t)e * 16 + 8];
        *(uint4*)&h2p[g][12] = *(const uint4*)&g_h2b[(size_t)e * 16 + 12];
    }

    union ABu { bf16x8s v; unsigned int u[4]; };
    f32x4 acc[2][2];
#pragma unroll
    for (int g = 0; g < 2; ++g) {
        acc[g][0] = (f32x4){0.f, 0.f, 0.f, 0.f};
        acc[g][1] = (f32x4){0.f, 0.f, 0.f, 0.f};
    }

#define EDGE_STEP(S, B0V, B1V)                                                                   \
    do {                                                                                          \
        _Pragma("unroll")                                                                         \
        for (int g = 0; g < 2; ++g) {                                                             \
            const unsigned int hw = h2p[g][(S) >> 1];                                             \
            const float hs = ((S)&1) ? bfhi(hw) : bflo(hw);                                       \
            ABu A;                                                                                \
            CVTPK(A.u[0], hs * u0[g].x, hs * u0[g].y);                                            \
            CVTPK(A.u[1], hs * u0[g].z, hs * u0[g].w);                                            \
            CVTPK(A.u[2], hs * u1[g].x, hs * u1[g].y);                                            \
            CVTPK(A.u[3], hs * u1[g].z, hs * u1[g].w);                                            \
            acc[g][0] = __builtin_amdgcn_mfma_f32_16x16x32_bf16(A.v, B0V, acc[g][0], 0, 0, 0);    \
            acc[g][1] = __builtin_amdgcn_mfma_f32_16x16x32_bf16(A.v, B1V, acc[g][1], 0, 0, 0);    \
        }                                                                                         \
    } while (0)

    // current / next 4-row banks, all named registers
    bf16x8s ca0 = B[0 * 128 + lane], cb0 = B[0 * 128 + 64 + lane];
    bf16x8s ca1 = B[1 * 128 + lane], cb1 = B[1 * 128 + 64 + lane];
    bf16x8s ca2 = B[2 * 128 + lane], cb2 = B[2 * 128 + 64 + lane];
    bf16x8s ca3 = B[3 * 128 + lane], cb3 = B[3 * 128 + 64 + lane];
    bf16x8s na0, nb0, na1, nb1, na2, nb2, na3, nb3;

#pragma unroll
    for (int blk = 0; blk < 8; ++blk) {
        if (blk < 7) {   // compile-time under unroll
            const int r = blk * 4 + 4;
            na0 = B[(r + 0) * 128 + lane]; nb0 = B[(r + 0) * 128 + 64 + lane];
            na1 = B[(r + 1) * 128 + lane]; nb1 = B[(r + 1) * 128 + 64 + lane];
            na2 = B[(r + 2) * 128 + lane]; nb2 = B[(r + 2) * 128 + 64 + lane];
            na3 = B[(r + 3) * 128 + lane]; nb3 = B[(r + 3) * 128 + 64 + lane];
        }
        EDGE_STEP(blk * 4 + 0, ca0, cb0);
        EDGE_STEP(blk * 4 + 1, ca1, cb1);
        EDGE_STEP(blk * 4 + 2, ca2, cb2);
        EDGE_STEP(blk * 4 + 3, ca3, cb3);
        if (blk < 7) {
            ca0 = na0; cb0 = nb0; ca1 = na1; cb1 = nb1;
            ca2 = na2; cb2 = nb2; ca3 = na3; cb3 = nb3;
        }
    }
#undef EDGE_STEP

    {   // bias step: A = bf16(u), B = nn2_b fragments (loaded at kernel start)
#pragma unroll
        for (int g = 0; g < 2; ++g) {
            ABu Au;
            CVTPK(Au.u[0], u0[g].x, u0[g].y); CVTPK(Au.u[1], u0[g].z, u0[g].w);
            CVTPK(Au.u[2], u1[g].x, u1[g].y); CVTPK(Au.u[3], u1[g].z, u1[g].w);
            acc[g][0] = __builtin_amdgcn_mfma_f32_16x16x32_bf16(Au.v, bbias0, acc[g][0], 0, 0, 0);
            acc[g][1] = __builtin_amdgcn_mfma_f32_16x16x32_bf16(Au.v, bbias1, acc[g][1], 0, 0, 0);
        }
    }
    // D layout: row (edge-in-group) = quad*4 + r, col (output) = lane&15. Plain stores.
#pragma unroll
    for (int g = 0; g < 2; ++g)
#pragma unroll
        for (int r = 0; r < 4; ++r) {
            const int p = w * 32 + g * 16 + quad * 4 + r;
            g_msg[p * DD + col] = acc[g][0][r];
            g_msg[p * DD + 16 + col] = acc[g][1][r];
        }
}

// GRU node update via MFMA (split-bf16). msg segment-sum via coalesced LDS staging.
__global__ __launch_bounds__(256) void k_node_mfma(const float* __restrict__ cb,
                                                   const float* __restrict__ bih,
                                                   const float* __restrict__ bhh) {
    __shared__ float sm[4][16 * 36];      // m-transpose tile (pad 36)
    __shared__ float smsg[4][16 * 32];    // staged msg chunk per wave
    const int wid = threadIdx.x >> 6, lane = threadIdx.x & 63;
    const int nt = blockIdx.x * 4 + wid;
    if (nt >= NN / 16) return;            // 3125 tiles exactly
    const int nb = nt * 16;
    const int col = lane & 15, quad = lane >> 4;
    const bf16x8s* FB = g_gru_frag;
    float* smt = sm[wid];
    float* smm = smsg[wid];

    float hv8[8];
    *(float4*)&hv8[0] = *(const float4*)&g_out[(nb + col) * DD + quad * 8];
    *(float4*)&hv8[4] = *(const float4*)&g_out[(nb + col) * DD + quad * 8 + 4];
    bf16x8s hAh, hAl; split8(hv8, hAh, hAl);

    unsigned int nr0[4], nr1[4];
#pragma unroll
    for (int r = 0; r < 4; ++r) {
        const int node = nb + quad * 4 + r;
        nr0[r] = g_row[node];
        nr1[r] = g_row[node + 1];
    }
    const unsigned int e0t = g_row[nb], e1t = g_row[nb + 16];

    float agg0[4] = {0.f, 0.f, 0.f, 0.f};
    float agg1[4] = {0.f, 0.f, 0.f, 0.f};
    for (unsigned int ec = e0t; ec < e1t; ec += 16) {
        const int idx = min((int)ec * 32 + lane * 8, NE * 32 - 8);
        const float4 v0 = *(const float4*)&g_msg[idx];
        const float4 v1 = *(const float4*)&g_msg[idx + 4];
        *(float4*)&smm[lane * 8] = v0;
        *(float4*)&smm[lane * 8 + 4] = v1;
#pragma unroll
        for (int r = 0; r < 4; ++r) {
            const int lo = (int)max(nr0[r], ec) - (int)ec;
            const int hi = (int)min(nr1[r], ec + 16u) - (int)ec;
            for (int s = lo; s < hi; ++s) {
                agg0[r] += smm[s * 32 + col];
                agg1[r] += smm[s * 32 + 16 + col];
            }
        }
    }

    float invr[4];
#pragma unroll
    for (int r = 0; r < 4; ++r)
        invr[r] = 1.0f / fmaxf((float)(nr1[r] - nr0[r]), 1.0f);

    // m = relu(h@root + agg*inv + cb), D-layout (row = quad*4+r, col)
#pragma unroll
    for (int c = 0; c < 2; ++c) {
        const float cbv = cb[c * 16 + col];
        f32x4 aM;
#pragma unroll
        for (int r = 0; r < 4; ++r)
            aM[r] = fmaf((c == 0) ? agg0[r] : agg1[r], invr[r], cbv);
        const bf16x8s Bh = FB[(c * 2 + 0) * 64 + lane];
        const bf16x8s Bl = FB[(c * 2 + 1) * 64 + lane];
        aM = __builtin_amdgcn_mfma_f32_16x16x32_bf16(hAh, Bh, aM, 0, 0, 0);
        aM = __builtin_amdgcn_mfma_f32_16x16x32_bf16(hAl, Bh, aM, 0, 0, 0);
        aM = __builtin_amdgcn_mfma_f32_16x16x32_bf16(hAh, Bl, aM, 0, 0, 0);
#pragma unroll
        for (int r = 0; r < 4; ++r)
            smt[(quad * 4 + r) * 36 + c * 16 + col] = fmaxf(aM[r], 0.f);
    }

    float mv8[8];
    *(float4*)&mv8[0] = *(const float4*)&smt[col * 36 + quad * 8];
    *(float4*)&mv8[4] = *(const float4*)&smt[col * 36 + quad * 8 + 4];
    bf16x8s mAh, mAl; split8(mv8, mAh, mAl);

    f32x4 R[2], Z[2], XN[2], HN[2];
#pragma unroll
    for (int c = 0; c < 6; ++c) {
        const float bx = bih[c * 16 + col], bh = bhh[c * 16 + col];
        f32x4 aX = {bx, bx, bx, bx}, aH = {bh, bh, bh, bh};
        const bf16x8s WIhf = FB[(4 + c * 2) * 64 + lane];
        const bf16x8s WIlf = FB[(5 + c * 2) * 64 + lane];
        const bf16x8s WHhf = FB[(16 + c * 2) * 64 + lane];
        const bf16x8s WHlf = FB[(17 + c * 2) * 64 + lane];
        aX = __builtin_amdgcn_mfma_f32_16x16x32_bf16(mAh, WIhf, aX, 0, 0, 0);
        aX = __builtin_amdgcn_mfma_f32_16x16x32_bf16(mAl, WIhf, aX, 0, 0, 0);
        aX = __builtin_amdgcn_mfma_f32_16x16x32_bf16(mAh, WIlf, aX, 0, 0, 0);
        aH = __builtin_amdgcn_mfma_f32_16x16x32_bf16(hAh, WHhf, aH, 0, 0, 0);
        aH = __builtin_amdgcn_mfma_f32_16x16x32_bf16(hAl, WHhf, aH, 0, 0, 0);
        aH = __builtin_amdgcn_mfma_f32_16x16x32_bf16(hAh, WHlf, aH, 0, 0, 0);
        if (c < 2) {
#pragma unroll
            for (int r = 0; r < 4; ++r) R[c][r] = sigm(aX[r] + aH[r]);
        } else if (c < 4) {
#pragma unroll
            for (int r = 0; r < 4; ++r) Z[c - 2][r] = sigm(aX[r] + aH[r]);
        } else {
            XN[c - 4] = aX; HN[c - 4] = aH;
        }
    }
#pragma unroll
    for (int c = 0; c < 2; ++c)
#pragma unroll
        for (int r = 0; r < 4; ++r) {
            const int addr = (nb + quad * 4 + r) * DD + c * 16 + col;
            const float nv = tanhx(XN[c][r] + R[c][r] * HN[c][r]);
            const float hv = g_out[addr];
            g_out[addr] = (1.f - Z[c][r]) * nv + Z[c][r] * hv;
        }
}

// attention pass + (last block) fused LSTM step for the next iteration
__global__ __launch_bounds__(256) void k_att_f(const float* __restrict__ wih,
                                               const float* __restrict__ whh,
                                               const float* __restrict__ bih,
                                               const float* __restrict__ bhh,
                                               const int dolstm) {
    __shared__ float sq[DD];
    __shared__ float red[4][DD + 1];
    __shared__ int slast;
    __shared__ float qs[64], shl[DD], gg[128];
    if (threadIdx.x < DD) sq[threadIdx.x] = g_q[threadIdx.x];
    __syncthreads();
    float pe = 0.f;
    float pv[DD];
#pragma unroll
    for (int i = 0; i < DD; ++i) pv[i] = 0.f;
    for (int n = blockIdx.x * blockDim.x + threadIdx.x; n < NN; n += gridDim.x * blockDim.x) {
        float row[DD];
#pragma unroll
        for (int q = 0; q < 8; ++q) *(float4*)&row[4 * q] = *(const float4*)&g_out[n * DD + 4 * q];
        float dot = 0.f;
#pragma unroll
        for (int i = 0; i < DD; ++i) dot = fmaf(row[i], sq[i], dot);
        const float e = __expf(dot);
        pe += e;
#pragma unroll
        for (int i = 0; i < DD; ++i) pv[i] = fmaf(e, row[i], pv[i]);
    }
#pragma unroll
    for (int off = 32; off > 0; off >>= 1) {
        pe += __shfl_down(pe, off, 64);
#pragma unroll
        for (int i = 0; i < DD; ++i) pv[i] += __shfl_down(pv[i], off, 64);
    }
    const int wid = threadIdx.x >> 6, lane = threadIdx.x & 63;
    if (lane == 0) {
        red[wid][0] = pe;
#pragma unroll
        for (int i = 0; i < DD; ++i) red[wid][1 + i] = pv[i];
    }
    __syncthreads();
    if (threadIdx.x < DD + 1) {
        const float s = red[0][threadIdx.x] + red[1][threadIdx.x] + red[2][threadIdx.x] + red[3][threadIdx.x];
        atomicAdd(&g_part[threadIdx.x], s);
    }
    __threadfence();
    __syncthreads();
    if (threadIdx.x == 0) {
        const unsigned int o = atomicAdd(&g_cnt, 1u);
        slast = (o == (unsigned int)(gridDim.x - 1)) ? 1 : 0;
    }
    __syncthreads();
    if (!slast) return;
    __threadfence();
    const int t = threadIdx.x;
    if (dolstm) {
        if (t < DD) { qs[t] = g_q[t]; shl[t] = g_hl[t]; }
        else if (t < 64) qs[t] = g_part[1 + t - DD] / g_part[0];
        __syncthreads();
        if (t < 128) {
            float acc = bih[t] + bhh[t];
            for (int i = 0; i < 64; ++i) acc = fmaf(qs[i], wih[i * 128 + t], acc);
            for (int i = 0; i < DD; ++i) acc = fmaf(shl[i], whh[i * 128 + t], acc);
            gg[t] = acc;
        }
        __syncthreads();
        if (t < DD) {
            const float ig = sigm(gg[t]), fg = sigm(gg[DD + t]);
            const float g2 = tanhx(gg[2 * DD + t]), og = sigm(gg[3 * DD + t]);
            const float cc = fmaf(fg, g_cl[t], ig * g2);
            g_cl[t] = cc; const float hn = og * tanhx(cc); g_hl[t] = hn; g_q[t] = hn;
        }
        if (t >= DD && t < 2 * DD + 1) g_part[t - DD] = 0.f;
    }
    if (t == 0) g_cnt = 0u;
}

// readout: 256 blocks x 128 threads, p-loop split 4-way across lane-slices
__global__ __launch_bounds__(128) void k_readout(const int* __restrict__ nr,
                                                 const float* __restrict__ w1,
                                                 const float* __restrict__ b1,
                                                 const float* __restrict__ w2,
                                                 const float* __restrict__ b2,
                                                 float* __restrict__ yout) {
    __shared__ float sw1[192 * DD];
    __shared__ float sS1[DD];
    __shared__ float sw2[DD * AA];
    __shared__ float sb1[DD];
    __shared__ float sb2[AA];
    __shared__ float sred[32 * DD];
    for (int i = threadIdx.x; i < 192 * DD; i += 128) sw1[i] = w1[i];
    for (int i = threadIdx.x; i < DD * AA; i += 128) sw2[i] = w2[i];
    if (threadIdx.x < DD) sb1[threadIdx.x] = b1[threadIdx.x];
    if (threadIdx.x >= DD && threadIdx.x < DD + AA) sb2[threadIdx.x - DD] = b2[threadIdx.x - DD];
    __syncthreads();
    if (threadIdx.x < DD) {
        float s = 0.f;
        for (int c = 0; c < 64; ++c) s += sw1[(128 + c) * DD + threadIdx.x];
        sS1[threadIdx.x] = s;
    }
    __syncthreads();
    const int g = blockIdx.x;            // t-group 0..255
    const int t0 = g * 32;
    const int f = threadIdx.x & 31;      // t-offset == feature index
    const int slice = threadIdx.x >> 5;  // 0..3 p-slices
    const int rowbase = g >> 2, col = g & 3;
    float4 acc[8];
#pragma unroll
    for (int q = 0; q < 8; ++q) acc[q] = make_float4(0.f, 0.f, 0.f, 0.f);
    for (int pp = 0; pp < 32; ++pp) {
        const int p = slice * 32 + pp;
        const int node = nr[(p * 64 + rowbase) * 4 + col];
        const float v = g_out[node * DD + f];
#pragma unroll
        for (int q = 0; q < 8; ++q) fma4(acc[q], v, *(const float4*)&sw1[p * DD + 4 * q]);
    }
#pragma unroll
    for (int q = 0; q < 8; ++q) {
        acc[q].x += __shfl_xor(acc[q].x, 32, 64);
        acc[q].y += __shfl_xor(acc[q].y, 32, 64);
        acc[q].z += __shfl_xor(acc[q].z, 32, 64);
        acc[q].w += __shfl_xor(acc[q].w, 32, 64);
    }
    if (threadIdx.x >= 64 && threadIdx.x < 96) {
#pragma unroll
        for (int q = 0; q < 8; ++q) *(float4*)&sred[f * DD + 4 * q] = acc[q];
    }
    __syncthreads();
    if (threadIdx.x < 32) {
        const int pidx = g >> 2;
        const float poolv = (pidx < DD) ? g_q[pidx] : (g_part[1 + (pidx - DD)] / g_part[0]);
        float y[AA];
#pragma unroll
        for (int a = 0; a < AA; ++a) y[a] = sb2[a];
#pragma unroll
        for (int q = 0; q < 8; ++q) {
            const float4 o = *(const float4*)&sred[f * DD + 4 * q];
            const float vals[4] = {acc[q].x + o.x, acc[q].y + o.y, acc[q].z + o.z, acc[q].w + o.w};
#pragma unroll
            for (int cc = 0; cc < 4; ++cc) {
                const int d = 4 * q + cc;
                const float ad = fmaxf(fmaf(poolv, sS1[d], sb1[d]) + vals[cc], 0.f);
#pragma unroll
                for (int a = 0; a < AA; ++a) y[a] = fmaf(ad, sw2[d * AA + a], y[a]);
            }
        }
#pragma unroll
        for (int a = 0; a < AA; ++a) yout[(t0 + f) * AA + a] = y[a];
    }
}

extern "C" void kernel_launch(void* const* d_in, const int* in_sizes, int n_in,
                              void* d_out, int out_size, void* d_ws, size_t ws_size,
                              hipStream_t stream) {
    (void)in_sizes; (void)n_in; (void)out_size; (void)d_ws; (void)ws_size;
    const float* x        = (const float*)d_in[0];
    const int*   ei       = (const int*)d_in[1];
    const float* ea       = (const float*)d_in[2];
    const int*   nonring  = (const int*)d_in[3];
    const float* lin0_w   = (const float*)d_in[4];
    const float* lin0_b   = (const float*)d_in[5];
    const float* nn1_w    = (const float*)d_in[6];
    const float* nn1_b    = (const float*)d_in[7];
    const float* nn2_w    = (const float*)d_in[8];
    const float* nn2_b    = (const float*)d_in[9];
    const float* conv_root= (const float*)d_in[10];
    const float* conv_b   = (const float*)d_in[11];
    const float* gru_w_ih = (const float*)d_in[12];
    const float* gru_w_hh = (const float*)d_in[13];
    const float* gru_b_ih = (const float*)d_in[14];
    const float* gru_b_hh = (const float*)d_in[15];
    const float* lstm_w_ih= (const float*)d_in[16];
    const float* lstm_w_hh= (const float*)d_in[17];
    const float* lstm_b_ih= (const float*)d_in[18];
    const float* lstm_b_hh= (const float*)d_in[19];
    const float* lin1_w   = (const float*)d_in[20];
    const float* lin1_b   = (const float*)d_in[21];
    const float* lin2_w   = (const float*)d_in[22];
    const float* lin2_b   = (const float*)d_in[23];
    float* out = (float*)d_out;

    k_prep0<<<(NN * DD) / 256, 256, 0, stream>>>(x, lin0_w, lin0_b, nn2_w, nn2_b,
                                                 conv_root, gru_w_ih, gru_w_hh,
                                                 lstm_b_ih, lstm_b_hh);
    k_hist<<<NE / 256, 256, 0, stream>>>(ei);
    k_scanA<<<196, 256, 0, stream>>>();
    k_scanB<<<1, 256, 0, stream>>>();
    k_scanC<<<196, 256, 0, stream>>>();
    k_scatter<<<NE / 256, 256, 0, stream>>>(ei, ea, nn1_w, nn1_b);

    for (int it = 0; it < 6; ++it) {
        k_edge_mfma<<<1250, 256, 0, stream>>>();
        k_node_mfma<<<(NN / 16 + 3) / 4, 256, 0, stream>>>(conv_b, gru_b_ih, gru_b_hh);
    }
    for (int s = 0; s < 6; ++s) {
        k_att_f<<<196, 256, 0, stream>>>(lstm_w_ih, lstm_w_hh, lstm_b_ih, lstm_b_hh, (s < 5) ? 1 : 0);
    }
    k_readout<<<256, 128, 0, stream>>>(nonring, lin1_w, lin1_b, lin2_w, lin2_b, out);
}

// Round 16
// 399.138 us; speedup vs baseline: 2.3532x; 1.0012x over previous
//
#include <hip/hip_runtime.h>
#include <hip/hip_bf16.h>

#define NN 50000
#define NE 160000
#define NT 8192
#define DD 32
#define AA 6

typedef __attribute__((ext_vector_type(8))) short bf16x8s;
typedef __attribute__((ext_vector_type(4))) float f32x4;

// ---- static device scratch ----
__device__ float g_out[NN * DD];          // node features / GRU hidden (6.4 MB)
__device__ float g_msg[NE * DD];          // per-edge messages, dst-sorted (20.5 MB)
__device__ unsigned int g_h2b[NE * 16];   // relu(edge_attr@nn1_w+b), sorted order, bf16 pairs
__device__ int g_src[NE];                 // src node of sorted edge
__device__ unsigned int g_bcnt[NN];       // histogram bins
__device__ unsigned int g_row[NN + 1];    // CSR row_ptr (by dst)
__device__ unsigned int g_cur[NN];        // scatter cursors
__device__ unsigned int g_btot[256];
__device__ bf16x8s g_w2frag[33 * 2 * 64]; // prepacked W2 B-frags (66 KB, L2-resident)
__device__ bf16x8s g_gru_frag[28 * 64];   // prepacked GRU B-frags hi/lo (28 KB)
__device__ float g_hl[DD], g_cl[DD], g_q[DD], g_part[DD + 1];
__device__ unsigned int g_cnt;            // zero at module load; reset after each use

__device__ __forceinline__ float sigm(float x) { return 1.0f / (1.0f + __expf(-x)); }
__device__ __forceinline__ float tanhx(float x) { return 1.0f - 2.0f / (__expf(2.0f * x) + 1.0f); }
__device__ __forceinline__ unsigned short f2bf(float f) {
    unsigned int u = __float_as_uint(f);
    u = (u + 0x7fffu + ((u >> 16) & 1u)) >> 16;
    return (unsigned short)u;
}
__device__ __forceinline__ float bflo(unsigned int pk) { return __uint_as_float(pk << 16); }
__device__ __forceinline__ float bfhi(unsigned int pk) { return __uint_as_float(pk & 0xffff0000u); }
__device__ __forceinline__ void fma4(float4& a, float s, const float4 b) {
    a.x = fmaf(s, b.x, a.x); a.y = fmaf(s, b.y, a.y);
    a.z = fmaf(s, b.z, a.z); a.w = fmaf(s, b.w, a.w);
}
#define CVTPK(dst, lo, hi) asm("v_cvt_pk_bf16_f32 %0, %1, %2" : "=v"(dst) : "v"(lo), "v"(hi))
#define ALOAD(p)     __hip_atomic_load((p), __ATOMIC_RELAXED, __HIP_MEMORY_SCOPE_AGENT)
#define ASTORE(p, v) __hip_atomic_store((p), (v), __ATOMIC_RELAXED, __HIP_MEMORY_SCOPE_AGENT)

// split f32[8] into bf16 hi + bf16 residual-lo fragments (f32-equivalent via 3 MFMAs)
__device__ __forceinline__ void split8(const float* v, bf16x8s& hi, bf16x8s& lo) {
    union U { bf16x8s v; unsigned int u[4]; } H, L;
    CVTPK(H.u[0], v[0], v[1]); CVTPK(H.u[1], v[2], v[3]);
    CVTPK(H.u[2], v[4], v[5]); CVTPK(H.u[3], v[6], v[7]);
    float r[8];
#pragma unroll
    for (int q = 0; q < 4; ++q) {
        r[2 * q]     = v[2 * q]     - bflo(H.u[q]);
        r[2 * q + 1] = v[2 * q + 1] - bfhi(H.u[q]);
    }
    CVTPK(L.u[0], r[0], r[1]); CVTPK(L.u[1], r[2], r[3]);
    CVTPK(L.u[2], r[4], r[5]); CVTPK(L.u[3], r[6], r[7]);
    hi = H.v; lo = L.v;
}

// ---------- fused prep: init features + zero hist + W2/GRU frag prepack + LSTM step0 ----------
__global__ __launch_bounds__(256) void k_prep0(const float* __restrict__ x,
                                               const float* __restrict__ l0w,
                                               const float* __restrict__ l0b,
                                               const float* __restrict__ w2m,
                                               const float* __restrict__ b2m,
                                               const float* __restrict__ root,
                                               const float* __restrict__ wih,
                                               const float* __restrict__ whh,
                                               const float* __restrict__ lbih,
                                               const float* __restrict__ lbhh) {
    const int t = blockIdx.x * 256 + threadIdx.x;   // grid = NN*DD/256 = 6250 blocks
    {   // node init (all t)
        const int n = t >> 5, d = t & 31;
        float v = l0b[d];
        v = fmaf(x[n * 3 + 0], l0w[0 * DD + d], v);
        v = fmaf(x[n * 3 + 1], l0w[1 * DD + d], v);
        v = fmaf(x[n * 3 + 2], l0w[2 * DD + d], v);
        g_out[t] = fmaxf(v, 0.f);
    }
    if (t < NN) g_bcnt[t] = 0u;
    if (t < 33 * 2 * 64 * 8) {   // W2' frag prepack
        const int j = t & 7, l = (t >> 3) & 63, c = (t >> 9) & 1, s = t >> 10;
        const int kk = (l >> 4) * 8 + j;
        const int col = c * 16 + (l & 15);
        const float v = (s == 32) ? b2m[kk * DD + col] : w2m[(32 * s + kk) * DD + col];
        ((unsigned short*)g_w2frag)[t] = f2bf(v);
    }
    if (t < 28 * 64) {           // GRU frag prepack (hi/lo)
        const int lane = t & 63, f = t >> 6;
        const float* M; int ncols, c, part;
        if (f < 4)       { M = root; ncols = 32; c = f >> 1;        part = f & 1; }
        else if (f < 16) { M = wih;  ncols = 96; c = (f - 4) >> 1;  part = f & 1; }
        else             { M = whh;  ncols = 96; c = (f - 16) >> 1; part = f & 1; }
        unsigned short out8[8];
#pragma unroll
        for (int j = 0; j < 8; ++j) {
            const int k = (lane >> 4) * 8 + j;
            const float v = M[k * ncols + c * 16 + (lane & 15)];
            const unsigned short hi = f2bf(v);
            out8[j] = (part == 0) ? hi : f2bf(v - __uint_as_float((unsigned int)hi << 16));
        }
        g_gru_frag[f * 64 + lane] = *(bf16x8s*)out8;
    }
    if (t < DD) {                // Set2Set LSTM step 0 (biases only)
        const float ig = sigm(lbih[t] + lbhh[t]);
        const float g2 = tanhx(lbih[2 * DD + t] + lbhh[2 * DD + t]);
        const float og = sigm(lbih[3 * DD + t] + lbhh[3 * DD + t]);
        const float cc = ig * g2;
        g_cl[t] = cc; const float hn = og * tanhx(cc); g_hl[t] = hn;
        ASTORE(&g_q[t], hn);
    }
    if (t >= DD && t <= 2 * DD) ASTORE(&g_part[t - DD], 0.f);   // exactly DD+1 entries
    if (t == 520) ASTORE(&g_cnt, 0u);
}

// ---------- one-time sort of edges by dst (counting sort, CSR) ----------
__global__ __launch_bounds__(256) void k_hist(const int* __restrict__ ei) {
    const int e = blockIdx.x * 256 + threadIdx.x;   // exact E
    atomicAdd(&g_bcnt[ei[NE + e]], 1u);
}

__global__ __launch_bounds__(256) void k_scanA() {
    __shared__ unsigned int s[256];
    const int t = threadIdx.x;
    const int idx = blockIdx.x * 256 + t;
    const unsigned int c = (idx < NN) ? g_bcnt[idx] : 0u;
    s[t] = c;
    __syncthreads();
#pragma unroll
    for (int off = 1; off < 256; off <<= 1) {
        const unsigned int o = (t >= off) ? s[t - off] : 0u;
        __syncthreads();
        s[t] += o;
        __syncthreads();
    }
    if (idx < NN) g_row[idx] = s[t] - c;   // block-local exclusive
    if (t == 255) g_btot[blockIdx.x] = s[255];
}

// scanC with folded block-offset reduction (replaces scanB): block b adds sum(g_btot[0..b))
__global__ __launch_bounds__(256) void k_scanC() {
    __shared__ unsigned int s[256];
    const int t = threadIdx.x;
    s[t] = (t < 196 && t < blockIdx.x) ? g_btot[t] : 0u;
    __syncthreads();
#pragma unroll
    for (int off = 128; off > 0; off >>= 1) {
        if (t < off) s[t] += s[t + off];
        __syncthreads();
    }
    const unsigned int boff = s[0];
    const int idx = blockIdx.x * 256 + t;
    if (idx < NN) {
        const unsigned int v = g_row[idx] + boff;
        g_row[idx] = v;
        g_cur[idx] = v;
    }
    if (idx == 0) g_row[NN] = NE;
}

// scatter + fused h2: write src and relu(edge_attr@nn1_w+nn1_b) at the sorted position
__global__ __launch_bounds__(256) void k_scatter(const int* __restrict__ ei,
                                                 const float* __restrict__ ea,
                                                 const float* __restrict__ w,
                                                 const float* __restrict__ b) {
    const int e = blockIdx.x * 256 + threadIdx.x;   // exact E
    const int d = ei[NE + e];
    const unsigned int pos = atomicAdd(&g_cur[d], 1u);
    g_src[pos] = ei[e];
    float eav[7];
#pragma unroll
    for (int i = 0; i < 7; ++i) eav[i] = ea[e * 7 + i];
#pragma unroll
    for (int kp = 0; kp < 16; ++kp) {
        const int k0 = kp * 2;
        float a0 = b[k0], a1 = b[k0 + 1];
#pragma unroll
        for (int i = 0; i < 7; ++i) {
            a0 = fmaf(eav[i], w[i * DD + k0], a0);
            a1 = fmaf(eav[i], w[i * DD + k0 + 1], a1);
        }
        unsigned int pk;
        CVTPK(pk, fmaxf(a0, 0.f), fmaxf(a1, 0.f));
        g_h2b[(size_t)pos * 16 + kp] = pk;
    }
}

// Fused NNConv edge pass via MFMA: msg = z @ W2', z = h2 (x) u in registers.
// G=2 groups (32 edges)/wave, named-register double-buffered B pipeline. (4x verified)
__global__ __launch_bounds__(256) void k_edge_mfma() {
    const int wid = threadIdx.x >> 6, lane = threadIdx.x & 63;
    const int w = blockIdx.x * 4 + wid;              // 0..4999 (1250 blocks x 4 waves)
    const int col = lane & 15, quad = lane >> 4;
    const bf16x8s* __restrict__ B = g_w2frag;

    // bias row (consumed last) issued FIRST: ~30 steps of latency slack
    const bf16x8s bbias0 = B[32 * 128 + lane];
    const bf16x8s bbias1 = B[32 * 128 + 64 + lane];

    float4 u0[2], u1[2];
    unsigned int h2p[2][16];
#pragma unroll
    for (int g = 0; g < 2; ++g) {
        const int e = w * 32 + g * 16 + col;
        const int src = g_src[e];
        u0[g] = *(const float4*)&g_out[src * DD + quad * 8];
        u1[g] = *(const float4*)&g_out[src * DD + quad * 8 + 4];
        *(uint4*)&h2p[g][0]  = *(const uint4*)&g_h2b[(size_t)e * 16];
        *(uint4*)&h2p[g][4]  = *(const uint4*)&g_h2b[(size_t)e * 16 + 4];
        *(uint4*)&h2p[g][8]  = *(const uint4*)&g_h2b[(size_t)e * 16 + 8];
        *(uint4*)&h2p[g][12] = *(const uint4*)&g_h2b[(size_t)e * 16 + 12];
    }

    union ABu { bf16x8s v; unsigned int u[4]; };
    f32x4 acc[2][2];
#pragma unroll
    for (int g = 0; g < 2; ++g) {
        acc[g][0] = (f32x4){0.f, 0.f, 0.f, 0.f};
        acc[g][1] = (f32x4){0.f, 0.f, 0.f, 0.f};
    }

#define EDGE_STEP(S, B0V, B1V)                                                                   \
    do {                                                                                          \
        _Pragma("unroll")                                                                         \
        for (int g = 0; g < 2; ++g) {                                                             \
            const unsigned int hw = h2p[g][(S) >> 1];                                             \
            const float hs = ((S)&1) ? bfhi(hw) : bflo(hw);                                       \
            ABu A;                                                                                \
            CVTPK(A.u[0], hs * u0[g].x, hs * u0[g].y);                                            \
            CVTPK(A.u[1], hs * u0[g].z, hs * u0[g].w);                                            \
            CVTPK(A.u[2], hs * u1[g].x, hs * u1[g].y);                                            \
            CVTPK(A.u[3], hs * u1[g].z, hs * u1[g].w);                                            \
            acc[g][0] = __builtin_amdgcn_mfma_f32_16x16x32_bf16(A.v, B0V, acc[g][0], 0, 0, 0);    \
            acc[g][1] = __builtin_amdgcn_mfma_f32_16x16x32_bf16(A.v, B1V, acc[g][1], 0, 0, 0);    \
        }                                                                                         \
    } while (0)

    // current / next 4-row banks, all named registers
    bf16x8s ca0 = B[0 * 128 + lane], cb0 = B[0 * 128 + 64 + lane];
    bf16x8s ca1 = B[1 * 128 + lane], cb1 = B[1 * 128 + 64 + lane];
    bf16x8s ca2 = B[2 * 128 + lane], cb2 = B[2 * 128 + 64 + lane];
    bf16x8s ca3 = B[3 * 128 + lane], cb3 = B[3 * 128 + 64 + lane];
    bf16x8s na0, nb0, na1, nb1, na2, nb2, na3, nb3;

#pragma unroll
    for (int blk = 0; blk < 8; ++blk) {
        if (blk < 7) {   // compile-time under unroll
            const int r = blk * 4 + 4;
            na0 = B[(r + 0) * 128 + lane]; nb0 = B[(r + 0) * 128 + 64 + lane];
            na1 = B[(r + 1) * 128 + lane]; nb1 = B[(r + 1) * 128 + 64 + lane];
            na2 = B[(r + 2) * 128 + lane]; nb2 = B[(r + 2) * 128 + 64 + lane];
            na3 = B[(r + 3) * 128 + lane]; nb3 = B[(r + 3) * 128 + 64 + lane];
        }
        EDGE_STEP(blk * 4 + 0, ca0, cb0);
        EDGE_STEP(blk * 4 + 1, ca1, cb1);
        EDGE_STEP(blk * 4 + 2, ca2, cb2);
        EDGE_STEP(blk * 4 + 3, ca3, cb3);
        if (blk < 7) {
            ca0 = na0; cb0 = nb0; ca1 = na1; cb1 = nb1;
            ca2 = na2; cb2 = nb2; ca3 = na3; cb3 = nb3;
        }
    }
#undef EDGE_STEP

    {   // bias step: A = bf16(u), B = nn2_b fragments (loaded at kernel start)
#pragma unroll
        for (int g = 0; g < 2; ++g) {
            ABu Au;
            CVTPK(Au.u[0], u0[g].x, u0[g].y); CVTPK(Au.u[1], u0[g].z, u0[g].w);
            CVTPK(Au.u[2], u1[g].x, u1[g].y); CVTPK(Au.u[3], u1[g].z, u1[g].w);
            acc[g][0] = __builtin_amdgcn_mfma_f32_16x16x32_bf16(Au.v, bbias0, acc[g][0], 0, 0, 0);
            acc[g][1] = __builtin_amdgcn_mfma_f32_16x16x32_bf16(Au.v, bbias1, acc[g][1], 0, 0, 0);
        }
    }
    // D layout: row (edge-in-group) = quad*4 + r, col (output) = lane&15. Plain stores.
#pragma unroll
    for (int g = 0; g < 2; ++g)
#pragma unroll
        for (int r = 0; r < 4; ++r) {
            const int p = w * 32 + g * 16 + quad * 4 + r;
            g_msg[p * DD + col] = acc[g][0][r];
            g_msg[p * DD + 16 + col] = acc[g][1][r];
        }
}

// GRU node update via MFMA (split-bf16). msg segment-sum via DOUBLE-BUFFERED LDS staging:
// chunk i+1's global load overlaps chunk i's summation (order preserved).
__global__ __launch_bounds__(256) void k_node_mfma(const float* __restrict__ cb,
                                                   const float* __restrict__ bih,
                                                   const float* __restrict__ bhh) {
    __shared__ float sm[4][16 * 36];      // m-transpose tile (pad 36)
    __shared__ float smsg[4][2][16 * 32]; // double-buffered msg chunks per wave (16 KB)
    const int wid = threadIdx.x >> 6, lane = threadIdx.x & 63;
    const int nt = blockIdx.x * 4 + wid;
    if (nt >= NN / 16) return;            // 3125 tiles exactly
    const int nb = nt * 16;
    const int col = lane & 15, quad = lane >> 4;
    const bf16x8s* FB = g_gru_frag;
    float* smt = sm[wid];

    float hv8[8];
    *(float4*)&hv8[0] = *(const float4*)&g_out[(nb + col) * DD + quad * 8];
    *(float4*)&hv8[4] = *(const float4*)&g_out[(nb + col) * DD + quad * 8 + 4];
    bf16x8s hAh, hAl; split8(hv8, hAh, hAl);

    unsigned int nr0[4], nr1[4];
#pragma unroll
    for (int r = 0; r < 4; ++r) {
        const int node = nb + quad * 4 + r;
        nr0[r] = g_row[node];
        nr1[r] = g_row[node + 1];
    }
    const unsigned int e0t = g_row[nb], e1t = g_row[nb + 16];

    float agg0[4] = {0.f, 0.f, 0.f, 0.f};
    float agg1[4] = {0.f, 0.f, 0.f, 0.f};
    // prologue: load chunk 0 into registers
    float4 v0, v1;
    {
        const int idx = min((int)e0t * 32 + lane * 8, NE * 32 - 8);
        v0 = *(const float4*)&g_msg[idx];
        v1 = *(const float4*)&g_msg[idx + 4];
    }
    int buf = 0;
    for (unsigned int ec = e0t; ec < e1t; ec += 16) {
        float* sb = &smsg[wid][buf][0];
        *(float4*)&sb[lane * 8] = v0;
        *(float4*)&sb[lane * 8 + 4] = v1;
        if (ec + 16 < e1t) {   // issue next chunk load; overlaps with summation below
            const int idx = min((int)(ec + 16) * 32 + lane * 8, NE * 32 - 8);
            v0 = *(const float4*)&g_msg[idx];
            v1 = *(const float4*)&g_msg[idx + 4];
        }
#pragma unroll
        for (int r = 0; r < 4; ++r) {
            const int lo = (int)max(nr0[r], ec) - (int)ec;
            const int hi = (int)min(nr1[r], ec + 16u) - (int)ec;
            for (int s = lo; s < hi; ++s) {
                agg0[r] += sb[s * 32 + col];
                agg1[r] += sb[s * 32 + 16 + col];
            }
        }
        buf ^= 1;
    }

    float invr[4];
#pragma unroll
    for (int r = 0; r < 4; ++r)
        invr[r] = 1.0f / fmaxf((float)(nr1[r] - nr0[r]), 1.0f);

    // m = relu(h@root + agg*inv + cb), D-layout (row = quad*4+r, col)
#pragma unroll
    for (int c = 0; c < 2; ++c) {
        const float cbv = cb[c * 16 + col];
        f32x4 aM;
#pragma unroll
        for (int r = 0; r < 4; ++r)
            aM[r] = fmaf((c == 0) ? agg0[r] : agg1[r], invr[r], cbv);
        const bf16x8s Bh = FB[(c * 2 + 0) * 64 + lane];
        const bf16x8s Bl = FB[(c * 2 + 1) * 64 + lane];
        aM = __builtin_amdgcn_mfma_f32_16x16x32_bf16(hAh, Bh, aM, 0, 0, 0);
        aM = __builtin_amdgcn_mfma_f32_16x16x32_bf16(hAl, Bh, aM, 0, 0, 0);
        aM = __builtin_amdgcn_mfma_f32_16x16x32_bf16(hAh, Bl, aM, 0, 0, 0);
#pragma unroll
        for (int r = 0; r < 4; ++r)
            smt[(quad * 4 + r) * 36 + c * 16 + col] = fmaxf(aM[r], 0.f);
    }

    float mv8[8];
    *(float4*)&mv8[0] = *(const float4*)&smt[col * 36 + quad * 8];
    *(float4*)&mv8[4] = *(const float4*)&smt[col * 36 + quad * 8 + 4];
    bf16x8s mAh, mAl; split8(mv8, mAh, mAl);

    f32x4 R[2], Z[2], XN[2], HN[2];
#pragma unroll
    for (int c = 0; c < 6; ++c) {
        const float bx = bih[c * 16 + col], bh = bhh[c * 16 + col];
        f32x4 aX = {bx, bx, bx, bx}, aH = {bh, bh, bh, bh};
        const bf16x8s WIhf = FB[(4 + c * 2) * 64 + lane];
        const bf16x8s WIlf = FB[(5 + c * 2) * 64 + lane];
        const bf16x8s WHhf = FB[(16 + c * 2) * 64 + lane];
        const bf16x8s WHlf = FB[(17 + c * 2) * 64 + lane];
        aX = __builtin_amdgcn_mfma_f32_16x16x32_bf16(mAh, WIhf, aX, 0, 0, 0);
        aX = __builtin_amdgcn_mfma_f32_16x16x32_bf16(mAl, WIhf, aX, 0, 0, 0);
        aX = __builtin_amdgcn_mfma_f32_16x16x32_bf16(mAh, WIlf, aX, 0, 0, 0);
        aH = __builtin_amdgcn_mfma_f32_16x16x32_bf16(hAh, WHhf, aH, 0, 0, 0);
        aH = __builtin_amdgcn_mfma_f32_16x16x32_bf16(hAl, WHhf, aH, 0, 0, 0);
        aH = __builtin_amdgcn_mfma_f32_16x16x32_bf16(hAh, WHlf, aH, 0, 0, 0);
        if (c < 2) {
#pragma unroll
            for (int r = 0; r < 4; ++r) R[c][r] = sigm(aX[r] + aH[r]);
        } else if (c < 4) {
#pragma unroll
            for (int r = 0; r < 4; ++r) Z[c - 2][r] = sigm(aX[r] + aH[r]);
        } else {
            XN[c - 4] = aX; HN[c - 4] = aH;
        }
    }
#pragma unroll
    for (int c = 0; c < 2; ++c)
#pragma unroll
        for (int r = 0; r < 4; ++r) {
            const int addr = (nb + quad * 4 + r) * DD + c * 16 + col;
            const float nv = tanhx(XN[c][r] + R[c][r] * HN[c][r]);
            const float hv = g_out[addr];
            g_out[addr] = (1.f - Z[c][r]) * nv + Z[c][r] * hv;
        }
}

// attention pass + (last block) fused LSTM step for the next iteration
__global__ __launch_bounds__(256) void k_att_f(const float* __restrict__ wih,
                                               const float* __restrict__ whh,
                                               const float* __restrict__ bih,
                                               const float* __restrict__ bhh,
                                               const int dolstm) {
    __shared__ float sq[DD];
    __shared__ float red[4][DD + 1];
    __shared__ int slast;
    __shared__ float qs[64], shl[DD], gg[128];
    if (threadIdx.x < DD) sq[threadIdx.x] = g_q[threadIdx.x];
    __syncthreads();
    float pe = 0.f;
    float pv[DD];
#pragma unroll
    for (int i = 0; i < DD; ++i) pv[i] = 0.f;
    for (int n = blockIdx.x * blockDim.x + threadIdx.x; n < NN; n += gridDim.x * blockDim.x) {
        float row[DD];
#pragma unroll
        for (int q = 0; q < 8; ++q) *(float4*)&row[4 * q] = *(const float4*)&g_out[n * DD + 4 * q];
        float dot = 0.f;
#pragma unroll
        for (int i = 0; i < DD; ++i) dot = fmaf(row[i], sq[i], dot);
        const float e = __expf(dot);
        pe += e;
#pragma unroll
        for (int i = 0; i < DD; ++i) pv[i] = fmaf(e, row[i], pv[i]);
    }
#pragma unroll
    for (int off = 32; off > 0; off >>= 1) {
        pe += __shfl_down(pe, off, 64);
#pragma unroll
        for (int i = 0; i < DD; ++i) pv[i] += __shfl_down(pv[i], off, 64);
    }
    const int wid = threadIdx.x >> 6, lane = threadIdx.x & 63;
    if (lane == 0) {
        red[wid][0] = pe;
#pragma unroll
        for (int i = 0; i < DD; ++i) red[wid][1 + i] = pv[i];
    }
    __syncthreads();
    if (threadIdx.x < DD + 1) {
        const float s = red[0][threadIdx.x] + red[1][threadIdx.x] + red[2][threadIdx.x] + red[3][threadIdx.x];
        atomicAdd(&g_part[threadIdx.x], s);
    }
    __threadfence();
    __syncthreads();
    if (threadIdx.x == 0) {
        const unsigned int o = atomicAdd(&g_cnt, 1u);
        slast = (o == (unsigned int)(gridDim.x - 1)) ? 1 : 0;
    }
    __syncthreads();
    if (!slast) return;
    __threadfence();
    const int t = threadIdx.x;
    if (dolstm) {
        if (t < DD) { qs[t] = g_q[t]; shl[t] = g_hl[t]; }
        else if (t < 64) qs[t] = g_part[1 + t - DD] / g_part[0];
        __syncthreads();
        if (t < 128) {
            float acc = bih[t] + bhh[t];
            for (int i = 0; i < 64; ++i) acc = fmaf(qs[i], wih[i * 128 + t], acc);
            for (int i = 0; i < DD; ++i) acc = fmaf(shl[i], whh[i * 128 + t], acc);
            gg[t] = acc;
        }
        __syncthreads();
        if (t < DD) {
            const float ig = sigm(gg[t]), fg = sigm(gg[DD + t]);
            const float g2 = tanhx(gg[2 * DD + t]), og = sigm(gg[3 * DD + t]);
            const float cc = fmaf(fg, g_cl[t], ig * g2);
            g_cl[t] = cc; const float hn = og * tanhx(cc); g_hl[t] = hn; g_q[t] = hn;
        }
        if (t >= DD && t < 2 * DD + 1) g_part[t - DD] = 0.f;
    }
    if (t == 0) g_cnt = 0u;
}

// readout: 256 blocks x 128 threads, p-loop split 4-way across lane-slices
__global__ __launch_bounds__(128) void k_readout(const int* __restrict__ nr,
                                                 const float* __restrict__ w1,
                                                 const float* __restrict__ b1,
                                                 const float* __restrict__ w2,
                                                 const float* __restrict__ b2,
                                                 float* __restrict__ yout) {
    __shared__ float sw1[192 * DD];
    __shared__ float sS1[DD];
    __shared__ float sw2[DD * AA];
    __shared__ float sb1[DD];
    __shared__ float sb2[AA];
    __shared__ float sred[32 * DD];
    for (int i = threadIdx.x; i < 192 * DD; i += 128) sw1[i] = w1[i];
    for (int i = threadIdx.x; i < DD * AA; i += 128) sw2[i] = w2[i];
    if (threadIdx.x < DD) sb1[threadIdx.x] = b1[threadIdx.x];
    if (threadIdx.x >= DD && threadIdx.x < DD + AA) sb2[threadIdx.x - DD] = b2[threadIdx.x - DD];
    __syncthreads();
    if (threadIdx.x < DD) {
        float s = 0.f;
        for (int c = 0; c < 64; ++c) s += sw1[(128 + c) * DD + threadIdx.x];
        sS1[threadIdx.x] = s;
    }
    __syncthreads();
    const int g = blockIdx.x;            // t-group 0..255
    const int t0 = g * 32;
    const int f = threadIdx.x & 31;      // t-offset == feature index
    const int slice = threadIdx.x >> 5;  // 0..3 p-slices
    const int rowbase = g >> 2, col = g & 3;
    float4 acc[8];
#pragma unroll
    for (int q = 0; q < 8; ++q) acc[q] = make_float4(0.f, 0.f, 0.f, 0.f);
    for (int pp = 0; pp < 32; ++pp) {
        const int p = slice * 32 + pp;
        const int node = nr[(p * 64 + rowbase) * 4 + col];
        const float v = g_out[node * DD + f];
#pragma unroll
        for (int q = 0; q < 8; ++q) fma4(acc[q], v, *(const float4*)&sw1[p * DD + 4 * q]);
    }
#pragma unroll
    for (int q = 0; q < 8; ++q) {
        acc[q].x += __shfl_xor(acc[q].x, 32, 64);
        acc[q].y += __shfl_xor(acc[q].y, 32, 64);
        acc[q].z += __shfl_xor(acc[q].z, 32, 64);
        acc[q].w += __shfl_xor(acc[q].w, 32, 64);
    }
    if (threadIdx.x >= 64 && threadIdx.x < 96) {
#pragma unroll
        for (int q = 0; q < 8; ++q) *(float4*)&sred[f * DD + 4 * q] = acc[q];
    }
    __syncthreads();
    if (threadIdx.x < 32) {
        const int pidx = g >> 2;
        const float poolv = (pidx < DD) ? g_q[pidx] : (g_part[1 + (pidx - DD)] / g_part[0]);
        float y[AA];
#pragma unroll
        for (int a = 0; a < AA; ++a) y[a] = sb2[a];
#pragma unroll
        for (int q = 0; q < 8; ++q) {
            const float4 o = *(const float4*)&sred[f * DD + 4 * q];
            const float vals[4] = {acc[q].x + o.x, acc[q].y + o.y, acc[q].z + o.z, acc[q].w + o.w};
#pragma unroll
            for (int cc = 0; cc < 4; ++cc) {
                const int d = 4 * q + cc;
                const float ad = fmaxf(fmaf(poolv, sS1[d], sb1[d]) + vals[cc], 0.f);
#pragma unroll
                for (int a = 0; a < AA; ++a) y[a] = fmaf(ad, sw2[d * AA + a], y[a]);
            }
        }
#pragma unroll
        for (int a = 0; a < AA; ++a) yout[(t0 + f) * AA + a] = y[a];
    }
}

extern "C" void kernel_launch(void* const* d_in, const int* in_sizes, int n_in,
                              void* d_out, int out_size, void* d_ws, size_t ws_size,
                              hipStream_t stream) {
    (void)in_sizes; (void)n_in; (void)out_size; (void)d_ws; (void)ws_size;
    const float* x        = (const float*)d_in[0];
    const int*   ei       = (const int*)d_in[1];
    const float* ea       = (const float*)d_in[2];
    const int*   nonring  = (const int*)d_in[3];
    const float* lin0_w   = (const float*)d_in[4];
    const float* lin0_b   = (const float*)d_in[5];
    const float* nn1_w    = (const float*)d_in[6];
    const float* nn1_b    = (const float*)d_in[7];
    const float* nn2_w    = (const float*)d_in[8];
    const float* nn2_b    = (const float*)d_in[9];
    const float* conv_root= (const float*)d_in[10];
    const float* conv_b   = (const float*)d_in[11];
    const float* gru_w_ih = (const float*)d_in[12];
    const float* gru_w_hh = (const float*)d_in[13];
    const float* gru_b_ih = (const float*)d_in[14];
    const float* gru_b_hh = (const float*)d_in[15];
    const float* lstm_w_ih= (const float*)d_in[16];
    const float* lstm_w_hh= (const float*)d_in[17];
    const float* lstm_b_ih= (const float*)d_in[18];
    const float* lstm_b_hh= (const float*)d_in[19];
    const float* lin1_w   = (const float*)d_in[20];
    const float* lin1_b   = (const float*)d_in[21];
    const float* lin2_w   = (const float*)d_in[22];
    const float* lin2_b   = (const float*)d_in[23];
    float* out = (float*)d_out;

    k_prep0<<<(NN * DD) / 256, 256, 0, stream>>>(x, lin0_w, lin0_b, nn2_w, nn2_b,
                                                 conv_root, gru_w_ih, gru_w_hh,
                                                 lstm_b_ih, lstm_b_hh);
    k_hist<<<NE / 256, 256, 0, stream>>>(ei);
    k_scanA<<<196, 256, 0, stream>>>();
    k_scanC<<<196, 256, 0, stream>>>();
    k_scatter<<<NE / 256, 256, 0, stream>>>(ei, ea, nn1_w, nn1_b);

    for (int it = 0; it < 6; ++it) {
        k_edge_mfma<<<1250, 256, 0, stream>>>();
        k_node_mfma<<<(NN / 16 + 3) / 4, 256, 0, stream>>>(conv_b, gru_b_ih, gru_b_hh);
    }
    for (int s = 0; s < 6; ++s) {
        k_att_f<<<196, 256, 0, stream>>>(lstm_w_ih, lstm_w_hh, lstm_b_ih, lstm_b_hh, (s < 5) ? 1 : 0);
    }
    k_readout<<<256, 128, 0, stream>>>(nonring, lin1_w, lin1_b, lin2_w, lin2_b, out);
}

// Round 17
// 398.170 us; speedup vs baseline: 2.3589x; 1.0024x over previous
//
#include <hip/hip_runtime.h>
#include <hip/hip_bf16.h>

#define NN 50000
#define NE 160000
#define NT 8192
#define DD 32
#define AA 6

typedef __attribute__((ext_vector_type(8))) short bf16x8s;
typedef __attribute__((ext_vector_type(4))) float f32x4;

// ---- static device scratch ----
__device__ float g_out[NN * DD];          // node features / GRU hidden (6.4 MB)
__device__ float g_msg[NE * DD];          // per-edge messages, dst-sorted (20.5 MB)
__device__ unsigned int g_h2b[NE * 16];   // relu(edge_attr@nn1_w+b), sorted order, bf16 pairs
__device__ int g_src[NE];                 // src node of sorted edge
__device__ unsigned int g_bcnt[NN];       // histogram bins (arrives zeroed; scanA re-zeroes)
__device__ unsigned int g_row[NN + 1];    // CSR row_ptr (by dst)
__device__ unsigned int g_cur[NN];        // scatter cursors
__device__ unsigned int g_btot[256];
__device__ bf16x8s g_w2frag[33 * 2 * 64]; // prepacked W2 B-frags (66 KB, L2-resident)
__device__ bf16x8s g_gru_frag[28 * 64];   // prepacked GRU B-frags hi/lo (28 KB)
__device__ float g_hl[DD], g_cl[DD], g_q[DD], g_part[DD + 1];
__device__ unsigned int g_cnt;            // zero at module load; reset after each use

__device__ __forceinline__ float sigm(float x) { return 1.0f / (1.0f + __expf(-x)); }
__device__ __forceinline__ float tanhx(float x) { return 1.0f - 2.0f / (__expf(2.0f * x) + 1.0f); }
__device__ __forceinline__ unsigned short f2bf(float f) {
    unsigned int u = __float_as_uint(f);
    u = (u + 0x7fffu + ((u >> 16) & 1u)) >> 16;
    return (unsigned short)u;
}
__device__ __forceinline__ float bflo(unsigned int pk) { return __uint_as_float(pk << 16); }
__device__ __forceinline__ float bfhi(unsigned int pk) { return __uint_as_float(pk & 0xffff0000u); }
__device__ __forceinline__ void fma4(float4& a, float s, const float4 b) {
    a.x = fmaf(s, b.x, a.x); a.y = fmaf(s, b.y, a.y);
    a.z = fmaf(s, b.z, a.z); a.w = fmaf(s, b.w, a.w);
}
#define CVTPK(dst, lo, hi) asm("v_cvt_pk_bf16_f32 %0, %1, %2" : "=v"(dst) : "v"(lo), "v"(hi))
#define ALOAD(p)     __hip_atomic_load((p), __ATOMIC_RELAXED, __HIP_MEMORY_SCOPE_AGENT)
#define ASTORE(p, v) __hip_atomic_store((p), (v), __ATOMIC_RELAXED, __HIP_MEMORY_SCOPE_AGENT)

// split f32[8] into bf16 hi + bf16 residual-lo fragments (f32-equivalent via 3 MFMAs)
__device__ __forceinline__ void split8(const float* v, bf16x8s& hi, bf16x8s& lo) {
    union U { bf16x8s v; unsigned int u[4]; } H, L;
    CVTPK(H.u[0], v[0], v[1]); CVTPK(H.u[1], v[2], v[3]);
    CVTPK(H.u[2], v[4], v[5]); CVTPK(H.u[3], v[6], v[7]);
    float r[8];
#pragma unroll
    for (int q = 0; q < 4; ++q) {
        r[2 * q]     = v[2 * q]     - bflo(H.u[q]);
        r[2 * q + 1] = v[2 * q + 1] - bfhi(H.u[q]);
    }
    CVTPK(L.u[0], r[0], r[1]); CVTPK(L.u[1], r[2], r[3]);
    CVTPK(L.u[2], r[4], r[5]); CVTPK(L.u[3], r[6], r[7]);
    hi = H.v; lo = L.v;
}

// ---------- fused prep: init features + edge histogram + frag prepack + LSTM step0 ----------
// g_bcnt arrives zeroed (module-load init on call 1; k_scanA read-and-reset thereafter).
__global__ __launch_bounds__(256) void k_prep0(const float* __restrict__ x,
                                               const int* __restrict__ ei,
                                               const float* __restrict__ l0w,
                                               const float* __restrict__ l0b,
                                               const float* __restrict__ w2m,
                                               const float* __restrict__ b2m,
                                               const float* __restrict__ root,
                                               const float* __restrict__ wih,
                                               const float* __restrict__ whh,
                                               const float* __restrict__ lbih,
                                               const float* __restrict__ lbhh) {
    const int t = blockIdx.x * 256 + threadIdx.x;   // grid = NN*DD/256 = 6250 blocks
    {   // node init (all t)
        const int n = t >> 5, d = t & 31;
        float v = l0b[d];
        v = fmaf(x[n * 3 + 0], l0w[0 * DD + d], v);
        v = fmaf(x[n * 3 + 1], l0w[1 * DD + d], v);
        v = fmaf(x[n * 3 + 2], l0w[2 * DD + d], v);
        g_out[t] = fmaxf(v, 0.f);
    }
    if (t < NE) atomicAdd(&g_bcnt[ei[NE + t]], 1u);   // histogram (bcnt pre-zeroed)
    if (t < 33 * 2 * 64 * 8) {   // W2' frag prepack
        const int j = t & 7, l = (t >> 3) & 63, c = (t >> 9) & 1, s = t >> 10;
        const int kk = (l >> 4) * 8 + j;
        const int col = c * 16 + (l & 15);
        const float v = (s == 32) ? b2m[kk * DD + col] : w2m[(32 * s + kk) * DD + col];
        ((unsigned short*)g_w2frag)[t] = f2bf(v);
    }
    if (t < 28 * 64) {           // GRU frag prepack (hi/lo)
        const int lane = t & 63, f = t >> 6;
        const float* M; int ncols, c, part;
        if (f < 4)       { M = root; ncols = 32; c = f >> 1;        part = f & 1; }
        else if (f < 16) { M = wih;  ncols = 96; c = (f - 4) >> 1;  part = f & 1; }
        else             { M = whh;  ncols = 96; c = (f - 16) >> 1; part = f & 1; }
        unsigned short out8[8];
#pragma unroll
        for (int j = 0; j < 8; ++j) {
            const int k = (lane >> 4) * 8 + j;
            const float v = M[k * ncols + c * 16 + (lane & 15)];
            const unsigned short hi = f2bf(v);
            out8[j] = (part == 0) ? hi : f2bf(v - __uint_as_float((unsigned int)hi << 16));
        }
        g_gru_frag[f * 64 + lane] = *(bf16x8s*)out8;
    }
    if (t < DD) {                // Set2Set LSTM step 0 (biases only)
        const float ig = sigm(lbih[t] + lbhh[t]);
        const float g2 = tanhx(lbih[2 * DD + t] + lbhh[2 * DD + t]);
        const float og = sigm(lbih[3 * DD + t] + lbhh[3 * DD + t]);
        const float cc = ig * g2;
        g_cl[t] = cc; const float hn = og * tanhx(cc); g_hl[t] = hn;
        ASTORE(&g_q[t], hn);
    }
    if (t >= DD && t <= 2 * DD) ASTORE(&g_part[t - DD], 0.f);   // exactly DD+1 entries
    if (t == 520) ASTORE(&g_cnt, 0u);
}

// ---------- one-time sort of edges by dst (counting sort, CSR) ----------
__global__ __launch_bounds__(256) void k_scanA() {
    __shared__ unsigned int s[256];
    const int t = threadIdx.x;
    const int idx = blockIdx.x * 256 + t;
    const unsigned int c = (idx < NN) ? g_bcnt[idx] : 0u;
    if (idx < NN) g_bcnt[idx] = 0u;        // reset for the NEXT kernel_launch call
    s[t] = c;
    __syncthreads();
#pragma unroll
    for (int off = 1; off < 256; off <<= 1) {
        const unsigned int o = (t >= off) ? s[t - off] : 0u;
        __syncthreads();
        s[t] += o;
        __syncthreads();
    }
    if (idx < NN) g_row[idx] = s[t] - c;   // block-local exclusive
    if (t == 255) g_btot[blockIdx.x] = s[255];
}

// scanC with folded block-offset reduction: block b adds sum(g_btot[0..b))
__global__ __launch_bounds__(256) void k_scanC() {
    __shared__ unsigned int s[256];
    const int t = threadIdx.x;
    s[t] = (t < 196 && t < blockIdx.x) ? g_btot[t] : 0u;
    __syncthreads();
#pragma unroll
    for (int off = 128; off > 0; off >>= 1) {
        if (t < off) s[t] += s[t + off];
        __syncthreads();
    }
    const unsigned int boff = s[0];
    const int idx = blockIdx.x * 256 + t;
    if (idx < NN) {
        const unsigned int v = g_row[idx] + boff;
        g_row[idx] = v;
        g_cur[idx] = v;
    }
    if (idx == 0) g_row[NN] = NE;
}

// scatter + fused h2: write src and relu(edge_attr@nn1_w+nn1_b) at the sorted position
__global__ __launch_bounds__(256) void k_scatter(const int* __restrict__ ei,
                                                 const float* __restrict__ ea,
                                                 const float* __restrict__ w,
                                                 const float* __restrict__ b) {
    const int e = blockIdx.x * 256 + threadIdx.x;   // exact E
    const int d = ei[NE + e];
    const unsigned int pos = atomicAdd(&g_cur[d], 1u);
    g_src[pos] = ei[e];
    float eav[7];
#pragma unroll
    for (int i = 0; i < 7; ++i) eav[i] = ea[e * 7 + i];
#pragma unroll
    for (int kp = 0; kp < 16; ++kp) {
        const int k0 = kp * 2;
        float a0 = b[k0], a1 = b[k0 + 1];
#pragma unroll
        for (int i = 0; i < 7; ++i) {
            a0 = fmaf(eav[i], w[i * DD + k0], a0);
            a1 = fmaf(eav[i], w[i * DD + k0 + 1], a1);
        }
        unsigned int pk;
        CVTPK(pk, fmaxf(a0, 0.f), fmaxf(a1, 0.f));
        g_h2b[(size_t)pos * 16 + kp] = pk;
    }
}

// Fused NNConv edge pass via MFMA: msg = z @ W2', z = h2 (x) u in registers.
// G=2 groups (32 edges)/wave, named-register double-buffered B pipeline. (5x verified)
__global__ __launch_bounds__(256) void k_edge_mfma() {
    const int wid = threadIdx.x >> 6, lane = threadIdx.x & 63;
    const int w = blockIdx.x * 4 + wid;              // 0..4999 (1250 blocks x 4 waves)
    const int col = lane & 15, quad = lane >> 4;
    const bf16x8s* __restrict__ B = g_w2frag;

    const bf16x8s bbias0 = B[32 * 128 + lane];
    const bf16x8s bbias1 = B[32 * 128 + 64 + lane];

    float4 u0[2], u1[2];
    unsigned int h2p[2][16];
#pragma unroll
    for (int g = 0; g < 2; ++g) {
        const int e = w * 32 + g * 16 + col;
        const int src = g_src[e];
        u0[g] = *(const float4*)&g_out[src * DD + quad * 8];
        u1[g] = *(const float4*)&g_out[src * DD + quad * 8 + 4];
        *(uint4*)&h2p[g][0]  = *(const uint4*)&g_h2b[(size_t)e * 16];
        *(uint4*)&h2p[g][4]  = *(const uint4*)&g_h2b[(size_t)e * 16 + 4];
        *(uint4*)&h2p[g][8]  = *(const uint4*)&g_h2b[(size_t)e * 16 + 8];
        *(uint4*)&h2p[g][12] = *(const uint4*)&g_h2b[(size_t)e * 16 + 12];
    }

    union ABu { bf16x8s v; unsigned int u[4]; };
    f32x4 acc[2][2];
#pragma unroll
    for (int g = 0; g < 2; ++g) {
        acc[g][0] = (f32x4){0.f, 0.f, 0.f, 0.f};
        acc[g][1] = (f32x4){0.f, 0.f, 0.f, 0.f};
    }

#define EDGE_STEP(S, B0V, B1V)                                                                   \
    do {                                                                                          \
        _Pragma("unroll")                                                                         \
        for (int g = 0; g < 2; ++g) {                                                             \
            const unsigned int hw = h2p[g][(S) >> 1];                                             \
            const float hs = ((S)&1) ? bfhi(hw) : bflo(hw);                                       \
            ABu A;                                                                                \
            CVTPK(A.u[0], hs * u0[g].x, hs * u0[g].y);                                            \
            CVTPK(A.u[1], hs * u0[g].z, hs * u0[g].w);                                            \
            CVTPK(A.u[2], hs * u1[g].x, hs * u1[g].y);                                            \
            CVTPK(A.u[3], hs * u1[g].z, hs * u1[g].w);                                            \
            acc[g][0] = __builtin_amdgcn_mfma_f32_16x16x32_bf16(A.v, B0V, acc[g][0], 0, 0, 0);    \
            acc[g][1] = __builtin_amdgcn_mfma_f32_16x16x32_bf16(A.v, B1V, acc[g][1], 0, 0, 0);    \
        }                                                                                         \
    } while (0)

    bf16x8s ca0 = B[0 * 128 + lane], cb0 = B[0 * 128 + 64 + lane];
    bf16x8s ca1 = B[1 * 128 + lane], cb1 = B[1 * 128 + 64 + lane];
    bf16x8s ca2 = B[2 * 128 + lane], cb2 = B[2 * 128 + 64 + lane];
    bf16x8s ca3 = B[3 * 128 + lane], cb3 = B[3 * 128 + 64 + lane];
    bf16x8s na0, nb0, na1, nb1, na2, nb2, na3, nb3;

#pragma unroll
    for (int blk = 0; blk < 8; ++blk) {
        if (blk < 7) {
            const int r = blk * 4 + 4;
            na0 = B[(r + 0) * 128 + lane]; nb0 = B[(r + 0) * 128 + 64 + lane];
            na1 = B[(r + 1) * 128 + lane]; nb1 = B[(r + 1) * 128 + 64 + lane];
            na2 = B[(r + 2) * 128 + lane]; nb2 = B[(r + 2) * 128 + 64 + lane];
            na3 = B[(r + 3) * 128 + lane]; nb3 = B[(r + 3) * 128 + 64 + lane];
        }
        EDGE_STEP(blk * 4 + 0, ca0, cb0);
        EDGE_STEP(blk * 4 + 1, ca1, cb1);
        EDGE_STEP(blk * 4 + 2, ca2, cb2);
        EDGE_STEP(blk * 4 + 3, ca3, cb3);
        if (blk < 7) {
            ca0 = na0; cb0 = nb0; ca1 = na1; cb1 = nb1;
            ca2 = na2; cb2 = nb2; ca3 = na3; cb3 = nb3;
        }
    }
#undef EDGE_STEP

    {   // bias step
#pragma unroll
        for (int g = 0; g < 2; ++g) {
            ABu Au;
            CVTPK(Au.u[0], u0[g].x, u0[g].y); CVTPK(Au.u[1], u0[g].z, u0[g].w);
            CVTPK(Au.u[2], u1[g].x, u1[g].y); CVTPK(Au.u[3], u1[g].z, u1[g].w);
            acc[g][0] = __builtin_amdgcn_mfma_f32_16x16x32_bf16(Au.v, bbias0, acc[g][0], 0, 0, 0);
            acc[g][1] = __builtin_amdgcn_mfma_f32_16x16x32_bf16(Au.v, bbias1, acc[g][1], 0, 0, 0);
        }
    }
#pragma unroll
    for (int g = 0; g < 2; ++g)
#pragma unroll
        for (int r = 0; r < 4; ++r) {
            const int p = w * 32 + g * 16 + quad * 4 + r;
            g_msg[p * DD + col] = acc[g][0][r];
            g_msg[p * DD + 16 + col] = acc[g][1][r];
        }
}

// GRU node update via MFMA (split-bf16). msg segment-sum via double-buffered LDS staging.
__global__ __launch_bounds__(256) void k_node_mfma(const float* __restrict__ cb,
                                                   const float* __restrict__ bih,
                                                   const float* __restrict__ bhh) {
    __shared__ float sm[4][16 * 36];      // m-transpose tile (pad 36)
    __shared__ float smsg[4][2][16 * 32]; // double-buffered msg chunks per wave
    const int wid = threadIdx.x >> 6, lane = threadIdx.x & 63;
    const int nt = blockIdx.x * 4 + wid;
    if (nt >= NN / 16) return;            // 3125 tiles exactly
    const int nb = nt * 16;
    const int col = lane & 15, quad = lane >> 4;
    const bf16x8s* FB = g_gru_frag;
    float* smt = sm[wid];

    float hv8[8];
    *(float4*)&hv8[0] = *(const float4*)&g_out[(nb + col) * DD + quad * 8];
    *(float4*)&hv8[4] = *(const float4*)&g_out[(nb + col) * DD + quad * 8 + 4];
    bf16x8s hAh, hAl; split8(hv8, hAh, hAl);

    unsigned int nr0[4], nr1[4];
#pragma unroll
    for (int r = 0; r < 4; ++r) {
        const int node = nb + quad * 4 + r;
        nr0[r] = g_row[node];
        nr1[r] = g_row[node + 1];
    }
    const unsigned int e0t = g_row[nb], e1t = g_row[nb + 16];

    float agg0[4] = {0.f, 0.f, 0.f, 0.f};
    float agg1[4] = {0.f, 0.f, 0.f, 0.f};
    float4 v0, v1;
    {
        const int idx = min((int)e0t * 32 + lane * 8, NE * 32 - 8);
        v0 = *(const float4*)&g_msg[idx];
        v1 = *(const float4*)&g_msg[idx + 4];
    }
    int buf = 0;
    for (unsigned int ec = e0t; ec < e1t; ec += 16) {
        float* sb = &smsg[wid][buf][0];
        *(float4*)&sb[lane * 8] = v0;
        *(float4*)&sb[lane * 8 + 4] = v1;
        if (ec + 16 < e1t) {
            const int idx = min((int)(ec + 16) * 32 + lane * 8, NE * 32 - 8);
            v0 = *(const float4*)&g_msg[idx];
            v1 = *(const float4*)&g_msg[idx + 4];
        }
#pragma unroll
        for (int r = 0; r < 4; ++r) {
            const int lo = (int)max(nr0[r], ec) - (int)ec;
            const int hi = (int)min(nr1[r], ec + 16u) - (int)ec;
            for (int s = lo; s < hi; ++s) {
                agg0[r] += sb[s * 32 + col];
                agg1[r] += sb[s * 32 + 16 + col];
            }
        }
        buf ^= 1;
    }

    float invr[4];
#pragma unroll
    for (int r = 0; r < 4; ++r)
        invr[r] = 1.0f / fmaxf((float)(nr1[r] - nr0[r]), 1.0f);

#pragma unroll
    for (int c = 0; c < 2; ++c) {
        const float cbv = cb[c * 16 + col];
        f32x4 aM;
#pragma unroll
        for (int r = 0; r < 4; ++r)
            aM[r] = fmaf((c == 0) ? agg0[r] : agg1[r], invr[r], cbv);
        const bf16x8s Bh = FB[(c * 2 + 0) * 64 + lane];
        const bf16x8s Bl = FB[(c * 2 + 1) * 64 + lane];
        aM = __builtin_amdgcn_mfma_f32_16x16x32_bf16(hAh, Bh, aM, 0, 0, 0);
        aM = __builtin_amdgcn_mfma_f32_16x16x32_bf16(hAl, Bh, aM, 0, 0, 0);
        aM = __builtin_amdgcn_mfma_f32_16x16x32_bf16(hAh, Bl, aM, 0, 0, 0);
#pragma unroll
        for (int r = 0; r < 4; ++r)
            smt[(quad * 4 + r) * 36 + c * 16 + col] = fmaxf(aM[r], 0.f);
    }

    float mv8[8];
    *(float4*)&mv8[0] = *(const float4*)&smt[col * 36 + quad * 8];
    *(float4*)&mv8[4] = *(const float4*)&smt[col * 36 + quad * 8 + 4];
    bf16x8s mAh, mAl; split8(mv8, mAh, mAl);

    f32x4 R[2], Z[2], XN[2], HN[2];
#pragma unroll
    for (int c = 0; c < 6; ++c) {
        const float bx = bih[c * 16 + col], bh = bhh[c * 16 + col];
        f32x4 aX = {bx, bx, bx, bx}, aH = {bh, bh, bh, bh};
        const bf16x8s WIhf = FB[(4 + c * 2) * 64 + lane];
        const bf16x8s WIlf = FB[(5 + c * 2) * 64 + lane];
        const bf16x8s WHhf = FB[(16 + c * 2) * 64 + lane];
        const bf16x8s WHlf = FB[(17 + c * 2) * 64 + lane];
        aX = __builtin_amdgcn_mfma_f32_16x16x32_bf16(mAh, WIhf, aX, 0, 0, 0);
        aX = __builtin_amdgcn_mfma_f32_16x16x32_bf16(mAl, WIhf, aX, 0, 0, 0);
        aX = __builtin_amdgcn_mfma_f32_16x16x32_bf16(mAh, WIlf, aX, 0, 0, 0);
        aH = __builtin_amdgcn_mfma_f32_16x16x32_bf16(hAh, WHhf, aH, 0, 0, 0);
        aH = __builtin_amdgcn_mfma_f32_16x16x32_bf16(hAl, WHhf, aH, 0, 0, 0);
        aH = __builtin_amdgcn_mfma_f32_16x16x32_bf16(hAh, WHlf, aH, 0, 0, 0);
        if (c < 2) {
#pragma unroll
            for (int r = 0; r < 4; ++r) R[c][r] = sigm(aX[r] + aH[r]);
        } else if (c < 4) {
#pragma unroll
            for (int r = 0; r < 4; ++r) Z[c - 2][r] = sigm(aX[r] + aH[r]);
        } else {
            XN[c - 4] = aX; HN[c - 4] = aH;
        }
    }
#pragma unroll
    for (int c = 0; c < 2; ++c)
#pragma unroll
        for (int r = 0; r < 4; ++r) {
            const int addr = (nb + quad * 4 + r) * DD + c * 16 + col;
            const float nv = tanhx(XN[c][r] + R[c][r] * HN[c][r]);
            const float hv = g_out[addr];
            g_out[addr] = (1.f - Z[c][r]) * nv + Z[c][r] * hv;
        }
}

// attention pass + (last block) fused LSTM step for the next iteration
__global__ __launch_bounds__(256) void k_att_f(const float* __restrict__ wih,
                                               const float* __restrict__ whh,
                                               const float* __restrict__ bih,
                                               const float* __restrict__ bhh,
                                               const int dolstm) {
    __shared__ float sq[DD];
    __shared__ float red[4][DD + 1];
    __shared__ int slast;
    __shared__ float qs[64], shl[DD], gg[128];
    if (threadIdx.x < DD) sq[threadIdx.x] = g_q[threadIdx.x];
    __syncthreads();
    float pe = 0.f;
    float pv[DD];
#pragma unroll
    for (int i = 0; i < DD; ++i) pv[i] = 0.f;
    for (int n = blockIdx.x * blockDim.x + threadIdx.x; n < NN; n += gridDim.x * blockDim.x) {
        float row[DD];
#pragma unroll
        for (int q = 0; q < 8; ++q) *(float4*)&row[4 * q] = *(const float4*)&g_out[n * DD + 4 * q];
        float dot = 0.f;
#pragma unroll
        for (int i = 0; i < DD; ++i) dot = fmaf(row[i], sq[i], dot);
        const float e = __expf(dot);
        pe += e;
#pragma unroll
        for (int i = 0; i < DD; ++i) pv[i] = fmaf(e, row[i], pv[i]);
    }
#pragma unroll
    for (int off = 32; off > 0; off >>= 1) {
        pe += __shfl_down(pe, off, 64);
#pragma unroll
        for (int i = 0; i < DD; ++i) pv[i] += __shfl_down(pv[i], off, 64);
    }
    const int wid = threadIdx.x >> 6, lane = threadIdx.x & 63;
    if (lane == 0) {
        red[wid][0] = pe;
#pragma unroll
        for (int i = 0; i < DD; ++i) red[wid][1 + i] = pv[i];
    }
    __syncthreads();
    if (threadIdx.x < DD + 1) {
        const float s = red[0][threadIdx.x] + red[1][threadIdx.x] + red[2][threadIdx.x] + red[3][threadIdx.x];
        atomicAdd(&g_part[threadIdx.x], s);
    }
    __threadfence();
    __syncthreads();
    if (threadIdx.x == 0) {
        const unsigned int o = atomicAdd(&g_cnt, 1u);
        slast = (o == (unsigned int)(gridDim.x - 1)) ? 1 : 0;
    }
    __syncthreads();
    if (!slast) return;
    __threadfence();
    const int t = threadIdx.x;
    if (dolstm) {
        if (t < DD) { qs[t] = g_q[t]; shl[t] = g_hl[t]; }
        else if (t < 64) qs[t] = g_part[1 + t - DD] / g_part[0];
        __syncthreads();
        if (t < 128) {
            float acc = bih[t] + bhh[t];
            for (int i = 0; i < 64; ++i) acc = fmaf(qs[i], wih[i * 128 + t], acc);
            for (int i = 0; i < DD; ++i) acc = fmaf(shl[i], whh[i * 128 + t], acc);
            gg[t] = acc;
        }
        __syncthreads();
        if (t < DD) {
            const float ig = sigm(gg[t]), fg = sigm(gg[DD + t]);
            const float g2 = tanhx(gg[2 * DD + t]), og = sigm(gg[3 * DD + t]);
            const float cc = fmaf(fg, g_cl[t], ig * g2);
            g_cl[t] = cc; const float hn = og * tanhx(cc); g_hl[t] = hn; g_q[t] = hn;
        }
        if (t >= DD && t < 2 * DD + 1) g_part[t - DD] = 0.f;
    }
    if (t == 0) g_cnt = 0u;
}

// readout: 256 blocks x 128 threads, p-loop split 4-way across lane-slices
__global__ __launch_bounds__(128) void k_readout(const int* __restrict__ nr,
                                                 const float* __restrict__ w1,
                                                 const float* __restrict__ b1,
                                                 const float* __restrict__ w2,
                                                 const float* __restrict__ b2,
                                                 float* __restrict__ yout) {
    __shared__ float sw1[192 * DD];
    __shared__ float sS1[DD];
    __shared__ float sw2[DD * AA];
    __shared__ float sb1[DD];
    __shared__ float sb2[AA];
    __shared__ float sred[32 * DD];
    for (int i = threadIdx.x; i < 192 * DD; i += 128) sw1[i] = w1[i];
    for (int i = threadIdx.x; i < DD * AA; i += 128) sw2[i] = w2[i];
    if (threadIdx.x < DD) sb1[threadIdx.x] = b1[threadIdx.x];
    if (threadIdx.x >= DD && threadIdx.x < DD + AA) sb2[threadIdx.x - DD] = b2[threadIdx.x - DD];
    __syncthreads();
    if (threadIdx.x < DD) {
        float s = 0.f;
        for (int c = 0; c < 64; ++c) s += sw1[(128 + c) * DD + threadIdx.x];
        sS1[threadIdx.x] = s;
    }
    __syncthreads();
    const int g = blockIdx.x;            // t-group 0..255
    const int t0 = g * 32;
    const int f = threadIdx.x & 31;      // t-offset == feature index
    const int slice = threadIdx.x >> 5;  // 0..3 p-slices
    const int rowbase = g >> 2, col = g & 3;
    float4 acc[8];
#pragma unroll
    for (int q = 0; q < 8; ++q) acc[q] = make_float4(0.f, 0.f, 0.f, 0.f);
    for (int pp = 0; pp < 32; ++pp) {
        const int p = slice * 32 + pp;
        const int node = nr[(p * 64 + rowbase) * 4 + col];
        const float v = g_out[node * DD + f];
#pragma unroll
        for (int q = 0; q < 8; ++q) fma4(acc[q], v, *(const float4*)&sw1[p * DD + 4 * q]);
    }
#pragma unroll
    for (int q = 0; q < 8; ++q) {
        acc[q].x += __shfl_xor(acc[q].x, 32, 64);
        acc[q].y += __shfl_xor(acc[q].y, 32, 64);
        acc[q].z += __shfl_xor(acc[q].z, 32, 64);
        acc[q].w += __shfl_xor(acc[q].w, 32, 64);
    }
    if (threadIdx.x >= 64 && threadIdx.x < 96) {
#pragma unroll
        for (int q = 0; q < 8; ++q) *(float4*)&sred[f * DD + 4 * q] = acc[q];
    }
    __syncthreads();
    if (threadIdx.x < 32) {
        const int pidx = g >> 2;
        const float poolv = (pidx < DD) ? g_q[pidx] : (g_part[1 + (pidx - DD)] / g_part[0]);
        float y[AA];
#pragma unroll
        for (int a = 0; a < AA; ++a) y[a] = sb2[a];
#pragma unroll
        for (int q = 0; q < 8; ++q) {
            const float4 o = *(const float4*)&sred[f * DD + 4 * q];
            const float vals[4] = {acc[q].x + o.x, acc[q].y + o.y, acc[q].z + o.z, acc[q].w + o.w};
#pragma unroll
            for (int cc = 0; cc < 4; ++cc) {
                const int d = 4 * q + cc;
                const float ad = fmaxf(fmaf(poolv, sS1[d], sb1[d]) + vals[cc], 0.f);
#pragma unroll
                for (int a = 0; a < AA; ++a) y[a] = fmaf(ad, sw2[d * AA + a], y[a]);
            }
        }
#pragma unroll
        for (int a = 0; a < AA; ++a) yout[(t0 + f) * AA + a] = y[a];
    }
}

extern "C" void kernel_launch(void* const* d_in, const int* in_sizes, int n_in,
                              void* d_out, int out_size, void* d_ws, size_t ws_size,
                              hipStream_t stream) {
    (void)in_sizes; (void)n_in; (void)out_size; (void)d_ws; (void)ws_size;
    const float* x        = (const float*)d_in[0];
    const int*   ei       = (const int*)d_in[1];
    const float* ea       = (const float*)d_in[2];
    const int*   nonring  = (const int*)d_in[3];
    const float* lin0_w   = (const float*)d_in[4];
    const float* lin0_b   = (const float*)d_in[5];
    const float* nn1_w    = (const float*)d_in[6];
    const float* nn1_b    = (const float*)d_in[7];
    const float* nn2_w    = (const float*)d_in[8];
    const float* nn2_b    = (const float*)d_in[9];
    const float* conv_root= (const float*)d_in[10];
    const float* conv_b   = (const float*)d_in[11];
    const float* gru_w_ih = (const float*)d_in[12];
    const float* gru_w_hh = (const float*)d_in[13];
    const float* gru_b_ih = (const float*)d_in[14];
    const float* gru_b_hh = (const float*)d_in[15];
    const float* lstm_w_ih= (const float*)d_in[16];
    const float* lstm_w_hh= (const float*)d_in[17];
    const float* lstm_b_ih= (const float*)d_in[18];
    const float* lstm_b_hh= (const float*)d_in[19];
    const float* lin1_w   = (const float*)d_in[20];
    const float* lin1_b   = (const float*)d_in[21];
    const float* lin2_w   = (const float*)d_in[22];
    const float* lin2_b   = (const float*)d_in[23];
    float* out = (float*)d_out;

    k_prep0<<<(NN * DD) / 256, 256, 0, stream>>>(x, ei, lin0_w, lin0_b, nn2_w, nn2_b,
                                                 conv_root, gru_w_ih, gru_w_hh,
                                                 lstm_b_ih, lstm_b_hh);
    k_scanA<<<196, 256, 0, stream>>>();
    k_scanC<<<196, 256, 0, stream>>>();
    k_scatter<<<NE / 256, 256, 0, stream>>>(ei, ea, nn1_w, nn1_b);

    for (int it = 0; it < 6; ++it) {
        k_edge_mfma<<<1250, 256, 0, stream>>>();
        k_node_mfma<<<(NN / 16 + 3) / 4, 256, 0, stream>>>(conv_b, gru_b_ih, gru_b_hh);
    }
    for (int s = 0; s < 6; ++s) {
        k_att_f<<<196, 256, 0, stream>>>(lstm_w_ih, lstm_w_hh, lstm_b_ih, lstm_b_hh, (s < 5) ? 1 : 0);
    }
    k_readout<<<256, 128, 0, stream>>>(nonring, lin1_w, lin1_b, lin2_w, lin2_b, out);
}